// Round 8
// baseline (437.007 us; speedup 1.0000x reference)
//
#include <hip/hip_runtime.h>
#include <stdint.h>

#define N_NODES 20000
#define N_EDGES 320000
#define EMB     256
#define D_IN    300
#define KPAD0   320   // D_IN padded to multiple of 32

// src-chunk bucketing: 2048 rows = 2MB of F, L2-sized. Buckets only ORDER the
// edge list per node (locality); aggregation runs one flat loop per node.
#define CHUNK_BITS 11
#define NC      10    // ceil(20000/2048)

// multi-block scan geometry
#define SCAN_L    (N_NODES * NC)          // 200000
#define SCAN_TPB  256
#define SCAN_VPT  4                       // elements per thread
#define SCAN_TILE (SCAN_TPB * SCAN_VPT)   // 1024
#define SCAN_NBLK ((SCAN_L + SCAN_TILE - 1) / SCAN_TILE)  // 196 (<= 256)

#define NSTRIP  (N_NODES / 32)            // 625 strips of 32 rows
#define LINB    256                       // persistent blocks for k_lin / k_lin320

typedef __attribute__((ext_vector_type(8))) short s16x8;   // 8 bf16 operand (4 VGPRs)
typedef __attribute__((ext_vector_type(4))) float f32x4;

static __device__ __forceinline__ float bf2f(unsigned short u) {
    union { unsigned u; float f; } x; x.u = ((unsigned)u) << 16; return x.f;
}
static __device__ __forceinline__ unsigned short f2bf(float f) {
    union { float f; unsigned u; } x; x.f = f;
    unsigned r = x.u + 0x7fffu + ((x.u >> 16) & 1u);   // RNE
    return (unsigned short)(r >> 16);
}
// split v = hi + lo (each bf16), |err| <= 2^-18 |v|
static __device__ __forceinline__ void split_bf(float v, unsigned short& h, unsigned short& l) {
    h = f2bf(v);
    l = f2bf(v - bf2f(h));
}

// ---------------- chunk-bucketed CSR build ----------------

__global__ void k_init2(int* deg2, int* cursor2, int n) {
    int i = blockIdx.x * 256 + threadIdx.x;
    if (i < n) { deg2[i] = 0; cursor2[i] = 0; }
}

__global__ void k_deg2(const int* __restrict__ src, const int* __restrict__ dst,
                       int* __restrict__ deg2, int e) {
    int i = blockIdx.x * 256 + threadIdx.x;
    if (i < e) {
        int s = src[i], d = dst[i];
        atomicAdd(&deg2[d * NC + (s >> CHUNK_BITS)], 1);
    }
}

// --- 3-phase multi-block exclusive scan over deg2[SCAN_L] -> ro2[0..SCAN_L] ---

__global__ __launch_bounds__(SCAN_TPB) void k_scan_part(
    const int* __restrict__ deg2, int* __restrict__ part)
{
    __shared__ int red[SCAN_TPB];
    int tid  = threadIdx.x;
    int base = blockIdx.x * SCAN_TILE + tid * SCAN_VPT;
    int s = 0;
#pragma unroll
    for (int u = 0; u < SCAN_VPT; ++u) {
        int i = base + u;
        s += (i < SCAN_L) ? deg2[i] : 0;
    }
    red[tid] = s;
    __syncthreads();
    for (int off = SCAN_TPB / 2; off > 0; off >>= 1) {
        if (tid < off) red[tid] += red[tid + off];
        __syncthreads();
    }
    if (tid == 0) part[blockIdx.x] = red[0];
}

__global__ __launch_bounds__(SCAN_TPB) void k_scan_root(int* part) {
    __shared__ int sh[SCAN_TPB];
    int tid = threadIdx.x;
    int v = (tid < SCAN_NBLK) ? part[tid] : 0;
    sh[tid] = v;
    __syncthreads();
    for (int off = 1; off < SCAN_TPB; off <<= 1) {
        int t = (tid >= off) ? sh[tid - off] : 0;
        __syncthreads();
        sh[tid] += t;
        __syncthreads();
    }
    if (tid < SCAN_NBLK) part[tid] = (tid == 0) ? 0 : sh[tid - 1];
}

__global__ __launch_bounds__(SCAN_TPB) void k_scan_write(
    const int* __restrict__ deg2, const int* __restrict__ part,
    int* __restrict__ ro2)
{
    __shared__ int red[SCAN_TPB];
    int tid  = threadIdx.x;
    int base = blockIdx.x * SCAN_TILE + tid * SCAN_VPT;
    int v[SCAN_VPT];
    int s = 0;
#pragma unroll
    for (int u = 0; u < SCAN_VPT; ++u) {
        int i = base + u;
        v[u] = (i < SCAN_L) ? deg2[i] : 0;
        s += v[u];
    }
    red[tid] = s;
    __syncthreads();
    for (int off = 1; off < SCAN_TPB; off <<= 1) {
        int t = (tid >= off) ? red[tid - off] : 0;
        __syncthreads();
        red[tid] += t;
        __syncthreads();
    }
    int excl = part[blockIdx.x] + ((tid == 0) ? 0 : red[tid - 1]);
#pragma unroll
    for (int u = 0; u < SCAN_VPT; ++u) {
        int i = base + u;
        if (i < SCAN_L) {
            ro2[i] = excl;
            excl += v[u];
            if (i == SCAN_L - 1) ro2[SCAN_L] = excl;   // total edges
        }
    }
}

__global__ void k_dinv(const int* __restrict__ ro2, float* __restrict__ dinv) {
    int n = blockIdx.x * 256 + threadIdx.x;
    if (n < N_NODES) {
        int d = ro2[(n + 1) * NC] - ro2[n * NC];
        dinv[n] = rsqrtf((float)(d + 1));   // +1 self-loop
    }
}

// packed edge record: {src, norm bits} -> one 8B load per edge
__global__ void k_scatter2(const int* __restrict__ src, const int* __restrict__ dst,
                           const int* __restrict__ ro2, int* __restrict__ cursor2,
                           const float* __restrict__ dinv,
                           int2* __restrict__ csr, int e) {
    int i = blockIdx.x * 256 + threadIdx.x;
    if (i >= e) return;
    int s = src[i], d = dst[i];
    int slot = d * NC + (s >> CHUNK_BITS);
    int pos = ro2[slot] + atomicAdd(&cursor2[slot], 1);
    float nrm = dinv[s] * dinv[d];
    csr[pos] = make_int2(s, __float_as_int(nrm));
}

// ------- batched weight transpose+split + x pre-split (1 dispatch) -------

struct WSplitArgs {
    const float* w[6];
    unsigned short* th[6];
    unsigned short* tl[6];
    const float* x;
    unsigned short* xh;
    unsigned short* xl;
};

__global__ void k_wsplit_all(WSplitArgs a) {
#pragma unroll
    for (int l = 0; l < 6; ++l) {
        const int K    = (l == 0) ? D_IN  : EMB;
        const int Kpad = (l == 0) ? KPAD0 : EMB;
        const int tot  = EMB * Kpad;
        for (int idx = blockIdx.x * 256 + threadIdx.x; idx < tot; idx += gridDim.x * 256) {
            int n = idx / Kpad, k = idx - n * Kpad;
            float v = (k < K) ? a.w[l][k * EMB + n] : 0.f;
            unsigned short h, lo;
            split_bf(v, h, lo);
            a.th[l][idx] = h; a.tl[l][idx] = lo;
        }
    }
    // x -> padded split planes [N_NODES][KPAD0]
    const int xt = N_NODES * KPAD0;
    for (int idx = blockIdx.x * 256 + threadIdx.x; idx < xt; idx += gridDim.x * 256) {
        int n = idx / KPAD0, k = idx - n * KPAD0;
        float v = (k < D_IN) ? a.x[(size_t)n * D_IN + k] : 0.f;
        unsigned short h, lo;
        split_bf(v, h, lo);
        a.xh[idx] = h; a.xl[idx] = lo;
    }
}

// ---------------- dedicated aggregation: wave-per-node, flat chunk-ordered loop ----------------
// Output written PRE-SPLIT as bf16 hi/lo planes (Ghi, Glo).

__global__ __launch_bounds__(256) void k_agg(
    const float* __restrict__ Fin,
    const int* __restrict__ ro2,
    const int2* __restrict__ csr,
    const float* __restrict__ dinv,
    const float* __restrict__ bagg,
    unsigned short* __restrict__ Ghi,
    unsigned short* __restrict__ Glo, int relu)
{
    int tid  = threadIdx.x;
    int lane = tid & 63, wave = tid >> 6;
    int node = blockIdx.x * 4 + wave;
    if (node >= N_NODES) return;

    const float4* F4 = (const float4*)Fin;
    float4 bb = *(const float4*)(bagg + lane * 4);

    float dv = dinv[node];
    float ws = dv * dv;
    float4 sv = F4[(size_t)node * 64 + lane];
    float a0 = bb.x + ws * sv.x;
    float a1 = bb.y + ws * sv.y;
    float a2 = bb.z + ws * sv.z;
    float a3 = bb.w + ws * sv.w;

    int j  = ro2[node * NC];
    int je = ro2[node * NC + NC];
    for (; j + 3 < je; j += 4) {
        int2 p0 = csr[j],     p1 = csr[j + 1];
        int2 p2 = csr[j + 2], p3 = csr[j + 3];
        float4 v0 = F4[(size_t)p0.x * 64 + lane];
        float4 v1 = F4[(size_t)p1.x * 64 + lane];
        float4 v2 = F4[(size_t)p2.x * 64 + lane];
        float4 v3 = F4[(size_t)p3.x * 64 + lane];
        float w0 = __int_as_float(p0.y), w1 = __int_as_float(p1.y);
        float w2 = __int_as_float(p2.y), w3 = __int_as_float(p3.y);
        a0 += w0 * v0.x + w1 * v1.x + w2 * v2.x + w3 * v3.x;
        a1 += w0 * v0.y + w1 * v1.y + w2 * v2.y + w3 * v3.y;
        a2 += w0 * v0.z + w1 * v1.z + w2 * v2.z + w3 * v3.z;
        a3 += w0 * v0.w + w1 * v1.w + w2 * v2.w + w3 * v3.w;
    }
    for (; j < je; ++j) {
        int2 p = csr[j];
        float w = __int_as_float(p.y);
        float4 v = F4[(size_t)p.x * 64 + lane];
        a0 += w * v.x; a1 += w * v.y; a2 += w * v.z; a3 += w * v.w;
    }

    if (relu) {
        a0 = fmaxf(a0, 0.f); a1 = fmaxf(a1, 0.f);
        a2 = fmaxf(a2, 0.f); a3 = fmaxf(a3, 0.f);
    }
    unsigned short h0, l0, h1, l1, h2, l2, h3, l3;
    split_bf(a0, h0, l0); split_bf(a1, h1, l1);
    split_bf(a2, h2, l2); split_bf(a3, h3, l3);
    ushort4 hv; hv.x = h0; hv.y = h1; hv.z = h2; hv.w = h3;
    ushort4 lv; lv.x = l0; lv.y = l1; lv.z = l2; lv.w = l3;
    *(ushort4*)(Ghi + (size_t)node * EMB + lane * 4) = hv;
    *(ushort4*)(Glo + (size_t)node * EMB + lane * 4) = lv;
}

// ---------------- persistent weight-stationary K=256 linear layer ----------------
// grid = 256 blocks (1/CU), 512 threads = 8 waves, wave owns 32 output cols.
// Weights (32 cols x 256 K, hi+lo) live in 128 VGPRs, loaded ONCE per wave.
// Blocks sweep 32-row strips (stride-256); A staged into XOR-swizzled LDS with
// a reg-staged 1-deep prefetch. MODE: 0 = f32 out (no bias); 1 = bias+relu ->
// split planes out; 2 = bias -> f32 out.

template<int MODE>
__global__ __launch_bounds__(512, 2) void k_lin(
    const unsigned short* __restrict__ Ahi,
    const unsigned short* __restrict__ Alo,
    const unsigned short* __restrict__ Wth,
    const unsigned short* __restrict__ Wtl,
    const float* __restrict__ bias,
    float* __restrict__ Cf,
    unsigned short* __restrict__ Chi,
    unsigned short* __restrict__ Clo)
{
    __shared__ unsigned short Sh[2][32][EMB];
    __shared__ unsigned short Sl[2][32][EMB];
    int tid  = threadIdx.x;
    int lane = tid & 63, wave = tid >> 6;         // 8 waves
    int quad = lane >> 4, l16 = lane & 15;

    // stationary weight fragments: wh/wl[ks][nt2]
    s16x8 wh[8][2], wl[8][2];
    {
        const unsigned short* bh = Wth + (size_t)(wave * 32 + l16) * EMB + quad * 8;
        const unsigned short* bl = Wtl + (size_t)(wave * 32 + l16) * EMB + quad * 8;
#pragma unroll
        for (int ks = 0; ks < 8; ++ks)
#pragma unroll
            for (int nt2 = 0; nt2 < 2; ++nt2) {
                wh[ks][nt2] = *(const s16x8*)(bh + (size_t)nt2 * 16 * EMB + ks * 32);
                wl[ks][nt2] = *(const s16x8*)(bl + (size_t)nt2 * 16 * EMB + ks * 32);
            }
    }
    float bb[2];
    if (MODE != 0) {
#pragma unroll
        for (int nt2 = 0; nt2 < 2; ++nt2) bb[nt2] = bias[wave * 32 + nt2 * 16 + l16];
    }

    int ns = (NSTRIP - blockIdx.x + (LINB - 1)) / LINB;   // 2 or 3 strips

    // staging map: u = tid + 512*i (i<4): plane=u>>10, row=(u>>5)&31, slot=u&31
    uint4 stg[4];
    {
        int nb0 = blockIdx.x * 32;
#pragma unroll
        for (int i = 0; i < 4; ++i) {
            int u = tid + 512 * i;
            int p = u >> 10, row = (u >> 5) & 31, s = u & 31;
            const unsigned short* srcp = (p ? Alo : Ahi) + (size_t)(nb0 + row) * EMB + s * 8;
            stg[i] = *(const uint4*)srcp;
        }
#pragma unroll
        for (int i = 0; i < 4; ++i) {
            int u = tid + 512 * i;
            int p = u >> 10, row = (u >> 5) & 31, s = u & 31;
            int sw = s ^ (row & 7);
            if (p) *(uint4*)&Sl[0][row][sw * 8] = stg[i];
            else   *(uint4*)&Sh[0][row][sw * 8] = stg[i];
        }
    }
    __syncthreads();

    for (int si = 0; si < ns; ++si) {
        int cur = si & 1;
        int nb = (blockIdx.x + si * LINB) * 32;

        // issue next strip's loads (hidden under MFMA phase)
        if (si + 1 < ns) {
            int nbn = (blockIdx.x + (si + 1) * LINB) * 32;
#pragma unroll
            for (int i = 0; i < 4; ++i) {
                int u = tid + 512 * i;
                int p = u >> 10, row = (u >> 5) & 31, s = u & 31;
                const unsigned short* srcp = (p ? Alo : Ahi) + (size_t)(nbn + row) * EMB + s * 8;
                stg[i] = *(const uint4*)srcp;
            }
        }

        f32x4 acc[2][2];
#pragma unroll
        for (int mt = 0; mt < 2; ++mt)
#pragma unroll
            for (int nt2 = 0; nt2 < 2; ++nt2) acc[mt][nt2] = (f32x4){0.f, 0.f, 0.f, 0.f};

#pragma unroll
        for (int ks = 0; ks < 8; ++ks) {
            s16x8 ah[2], al[2];
#pragma unroll
            for (int mt = 0; mt < 2; ++mt) {
                int row = mt * 16 + l16;
                int sw = (ks * 4 + quad) ^ (row & 7);
                ah[mt] = *(const s16x8*)&Sh[cur][row][sw * 8];
                al[mt] = *(const s16x8*)&Sl[cur][row][sw * 8];
            }
#pragma unroll
            for (int mt = 0; mt < 2; ++mt)
#pragma unroll
                for (int nt2 = 0; nt2 < 2; ++nt2) {
                    acc[mt][nt2] = __builtin_amdgcn_mfma_f32_16x16x32_bf16(ah[mt], wh[ks][nt2], acc[mt][nt2], 0, 0, 0);
                    acc[mt][nt2] = __builtin_amdgcn_mfma_f32_16x16x32_bf16(ah[mt], wl[ks][nt2], acc[mt][nt2], 0, 0, 0);
                    acc[mt][nt2] = __builtin_amdgcn_mfma_f32_16x16x32_bf16(al[mt], wh[ks][nt2], acc[mt][nt2], 0, 0, 0);
                }
        }

        // epilogue for strip si
#pragma unroll
        for (int mt = 0; mt < 2; ++mt)
#pragma unroll
            for (int r = 0; r < 4; ++r) {
                int row = nb + mt * 16 + quad * 4 + r;
#pragma unroll
                for (int nt2 = 0; nt2 < 2; ++nt2) {
                    int col = wave * 32 + nt2 * 16 + l16;
                    float v = acc[mt][nt2][r];
                    if (MODE == 0) {
                        Cf[(size_t)row * EMB + col] = v;
                    } else if (MODE == 1) {
                        v = fmaxf(v + bb[nt2], 0.f);
                        unsigned short h, l;
                        split_bf(v, h, l);
                        Chi[(size_t)row * EMB + col] = h;
                        Clo[(size_t)row * EMB + col] = l;
                    } else {
                        Cf[(size_t)row * EMB + col] = v + bb[nt2];
                    }
                }
            }

        // write next strip into the other LDS buffer; single barrier per strip
        if (si + 1 < ns) {
            int nxt = cur ^ 1;
#pragma unroll
            for (int i = 0; i < 4; ++i) {
                int u = tid + 512 * i;
                int p = u >> 10, row = (u >> 5) & 31, s = u & 31;
                int sw = s ^ (row & 7);
                if (p) *(uint4*)&Sl[nxt][row][sw * 8] = stg[i];
                else   *(uint4*)&Sh[nxt][row][sw * 8] = stg[i];
            }
            __syncthreads();
        }
    }
}

// ---------------- persistent weight-stationary K=320 conv0 GEMM ----------------
// Same design as k_lin but K=320 (10 ks-steps, 160 weight VGPRs), single-buffered
// 40KB LDS (static-64KB-safe), reg prefetch of next strip. f32 out, no bias.

__global__ __launch_bounds__(512, 1) void k_lin320(
    const unsigned short* __restrict__ Ahi,
    const unsigned short* __restrict__ Alo,
    const unsigned short* __restrict__ Wth,
    const unsigned short* __restrict__ Wtl,
    float* __restrict__ Cf)
{
    __shared__ unsigned short Sh[32][KPAD0];
    __shared__ unsigned short Sl[32][KPAD0];
    int tid  = threadIdx.x;
    int lane = tid & 63, wave = tid >> 6;         // 8 waves
    int quad = lane >> 4, l16 = lane & 15;

    // stationary weight fragments: wh/wl[ks][nt2], ks<10
    s16x8 wh[10][2], wl[10][2];
    {
        const unsigned short* bh = Wth + (size_t)(wave * 32 + l16) * KPAD0 + quad * 8;
        const unsigned short* bl = Wtl + (size_t)(wave * 32 + l16) * KPAD0 + quad * 8;
#pragma unroll
        for (int ks = 0; ks < 10; ++ks)
#pragma unroll
            for (int nt2 = 0; nt2 < 2; ++nt2) {
                wh[ks][nt2] = *(const s16x8*)(bh + (size_t)nt2 * 16 * KPAD0 + ks * 32);
                wl[ks][nt2] = *(const s16x8*)(bl + (size_t)nt2 * 16 * KPAD0 + ks * 32);
            }
    }

    int ns = (NSTRIP - blockIdx.x + (LINB - 1)) / LINB;

    // staging map: strip = 32 rows x 40 slots x 2 planes of uint4; 512 thr x 5
    uint4 stg[5];
    auto stage_load = [&](int nb) {
#pragma unroll
        for (int i = 0; i < 5; ++i) {
            int u = tid + 512 * i;
            int p = u / 1280, rem = u - p * 1280;
            int row = rem / 40, s = rem - row * 40;
            const unsigned short* srcp = (p ? Alo : Ahi) + (size_t)(nb + row) * KPAD0 + s * 8;
            stg[i] = *(const uint4*)srcp;
        }
    };
    auto stage_write = [&]() {
#pragma unroll
        for (int i = 0; i < 5; ++i) {
            int u = tid + 512 * i;
            int p = u / 1280, rem = u - p * 1280;
            int row = rem / 40, s = rem - row * 40;
            int sw = s ^ (row & 7);
            if (p) *(uint4*)&Sl[row][sw * 8] = stg[i];
            else   *(uint4*)&Sh[row][sw * 8] = stg[i];
        }
    };

    stage_load(blockIdx.x * 32);
    stage_write();
    __syncthreads();

    for (int si = 0; si < ns; ++si) {
        int nb = (blockIdx.x + si * LINB) * 32;

        if (si + 1 < ns) stage_load((blockIdx.x + (si + 1) * LINB) * 32);

        f32x4 acc[2][2];
#pragma unroll
        for (int mt = 0; mt < 2; ++mt)
#pragma unroll
            for (int nt2 = 0; nt2 < 2; ++nt2) acc[mt][nt2] = (f32x4){0.f, 0.f, 0.f, 0.f};

#pragma unroll
        for (int ks = 0; ks < 10; ++ks) {
            s16x8 ah[2], al[2];
#pragma unroll
            for (int mt = 0; mt < 2; ++mt) {
                int row = mt * 16 + l16;
                int sw = (ks * 4 + quad) ^ (row & 7);
                ah[mt] = *(const s16x8*)&Sh[row][sw * 8];
                al[mt] = *(const s16x8*)&Sl[row][sw * 8];
            }
#pragma unroll
            for (int mt = 0; mt < 2; ++mt)
#pragma unroll
                for (int nt2 = 0; nt2 < 2; ++nt2) {
                    acc[mt][nt2] = __builtin_amdgcn_mfma_f32_16x16x32_bf16(ah[mt], wh[ks][nt2], acc[mt][nt2], 0, 0, 0);
                    acc[mt][nt2] = __builtin_amdgcn_mfma_f32_16x16x32_bf16(ah[mt], wl[ks][nt2], acc[mt][nt2], 0, 0, 0);
                    acc[mt][nt2] = __builtin_amdgcn_mfma_f32_16x16x32_bf16(al[mt], wh[ks][nt2], acc[mt][nt2], 0, 0, 0);
                }
        }

#pragma unroll
        for (int mt = 0; mt < 2; ++mt)
#pragma unroll
            for (int r = 0; r < 4; ++r) {
                int row = nb + mt * 16 + quad * 4 + r;
#pragma unroll
                for (int nt2 = 0; nt2 < 2; ++nt2) {
                    int col = wave * 32 + nt2 * 16 + l16;
                    Cf[(size_t)row * EMB + col] = acc[mt][nt2][r];
                }
            }

        if (si + 1 < ns) {
            __syncthreads();   // all MFMA reads of LDS done
            stage_write();
            __syncthreads();
        }
    }
}

// ---------------- launch ----------------

extern "C" void kernel_launch(void* const* d_in, const int* in_sizes, int n_in,
                              void* d_out, int out_size, void* d_ws, size_t ws_size,
                              hipStream_t stream) {
    const float* x  = (const float*)d_in[0];
    const int*   ei = (const int*)d_in[1];
    const int* src = ei;
    const int* dst = ei + N_EDGES;

    const float* w[6] = {
        (const float*)d_in[2], (const float*)d_in[4], (const float*)d_in[6],
        (const float*)d_in[8], (const float*)d_in[10], (const float*)d_in[12] };
    const float* b[6] = {
        (const float*)d_in[3], (const float*)d_in[5], (const float*)d_in[7],
        (const float*)d_in[9], (const float*)d_in[11], (const float*)d_in[13] };

    char* wsp = (char*)d_ws;
    auto alloc = [&](size_t bytes) {
        char* p = wsp; wsp += (bytes + 255) & ~(size_t)255; return p;
    };
    int*   deg2     = (int*)alloc((size_t)N_NODES * NC * 4);
    int*   cursor2  = (int*)alloc((size_t)N_NODES * NC * 4);
    int*   ro2      = (int*)alloc(((size_t)N_NODES * NC + 1) * 4);
    int*   part     = (int*)alloc(SCAN_NBLK * 4);
    int2*  csr      = (int2*)alloc((size_t)N_EDGES * 8);
    float* dinv     = (float*)alloc(N_NODES * 4);
    unsigned short* wth[6];
    unsigned short* wtl[6];
    wth[0] = (unsigned short*)alloc(EMB * KPAD0 * 2);
    wtl[0] = (unsigned short*)alloc(EMB * KPAD0 * 2);
    for (int i = 1; i < 6; ++i) {
        wth[i] = (unsigned short*)alloc(EMB * EMB * 2);
        wtl[i] = (unsigned short*)alloc(EMB * EMB * 2);
    }
    unsigned short* Xhi = (unsigned short*)alloc((size_t)N_NODES * KPAD0 * 2);  // x planes
    unsigned short* Xlo = (unsigned short*)alloc((size_t)N_NODES * KPAD0 * 2);
    float* FA = (float*)alloc((size_t)N_NODES * EMB * 4);                     // f32 features
    unsigned short* Ghi = (unsigned short*)alloc((size_t)N_NODES * EMB * 2);  // plane pair A
    unsigned short* Glo = (unsigned short*)alloc((size_t)N_NODES * EMB * 2);
    unsigned short* Hhi = (unsigned short*)alloc((size_t)N_NODES * EMB * 2);  // plane pair B
    unsigned short* Hlo = (unsigned short*)alloc((size_t)N_NODES * EMB * 2);
    float* FB = (float*)d_out;                                                // d_out as scratch

    const int NB_E = (N_EDGES + 255) / 256;               // 1250
    const int NB_N = (N_NODES + 255) / 256;               // 79
    const int NB_I = (N_NODES * NC + 255) / 256;          // 782
    const int AB   = (N_NODES + 3) / 4;                   // 5000 (wave-per-node)

    // chunk-bucketed CSR build (multi-block scan)
    k_init2<<<NB_I, 256, 0, stream>>>(deg2, cursor2, N_NODES * NC);
    k_deg2<<<NB_E, 256, 0, stream>>>(src, dst, deg2, N_EDGES);
    k_scan_part<<<SCAN_NBLK, SCAN_TPB, 0, stream>>>(deg2, part);
    k_scan_root<<<1, SCAN_TPB, 0, stream>>>(part);
    k_scan_write<<<SCAN_NBLK, SCAN_TPB, 0, stream>>>(deg2, part, ro2);
    k_dinv<<<NB_N, 256, 0, stream>>>(ro2, dinv);
    k_scatter2<<<NB_E, 256, 0, stream>>>(src, dst, ro2, cursor2, dinv, csr, N_EDGES);

    // weights + x: transpose + hi/lo split
    WSplitArgs wa;
    for (int i = 0; i < 6; ++i) { wa.w[i] = w[i]; wa.th[i] = wth[i]; wa.tl[i] = wtl[i]; }
    wa.x = x; wa.xh = Xhi; wa.xl = Xlo;
    k_wsplit_all<<<320, 256, 0, stream>>>(wa);

    // conv0 gemm: x @ W0 -> FA (f32), weight-stationary persistent
    k_lin320<<<LINB, 512, 0, stream>>>(Xhi, Xlo, wth[0], wtl[0], FA);

    // conv1: agg(FA)+b0,relu -> G planes ; G @ W1 -> FB (f32)
    k_agg<<<AB, 256, 0, stream>>>(FA, ro2, csr, dinv, b[0], Ghi, Glo, 1);
    k_lin<0><<<LINB, 512, 0, stream>>>(Ghi, Glo, wth[1], wtl[1], nullptr, FB, nullptr, nullptr);

    // conv2: agg(FB)+b1,relu -> G planes ; G @ W2 -> FA (f32)
    k_agg<<<AB, 256, 0, stream>>>(FB, ro2, csr, dinv, b[1], Ghi, Glo, 1);
    k_lin<0><<<LINB, 512, 0, stream>>>(Ghi, Glo, wth[2], wtl[2], nullptr, FA, nullptr, nullptr);

    // tail: agg(FA)+b2 -> G planes ; mlp1 -> H planes ; mlp2 -> G planes ; mlp3 -> out
    k_agg<<<AB, 256, 0, stream>>>(FA, ro2, csr, dinv, b[2], Ghi, Glo, 0);
    k_lin<1><<<LINB, 512, 0, stream>>>(Ghi, Glo, wth[3], wtl[3], b[3], nullptr, Hhi, Hlo);
    k_lin<1><<<LINB, 512, 0, stream>>>(Hhi, Hlo, wth[4], wtl[4], b[4], nullptr, Ghi, Glo);
    k_lin<2><<<LINB, 512, 0, stream>>>(Ghi, Glo, wth[5], wtl[5], b[5], FB, nullptr, nullptr);
}

// Round 9
// 418.916 us; speedup vs baseline: 1.0432x; 1.0432x over previous
//
#include <hip/hip_runtime.h>
#include <stdint.h>

#define N_NODES 20000
#define N_EDGES 320000
#define EMB     256
#define D_IN    300
#define KPAD0   320   // D_IN padded to multiple of 32

// src-chunk bucketing: 2048 rows = 2MB of F, L2-sized. Buckets only ORDER the
// edge list per node (locality); aggregation runs one flat loop per node.
#define CHUNK_BITS 11
#define NC      10    // ceil(20000/2048)

// multi-block scan geometry
#define SCAN_L    (N_NODES * NC)          // 200000
#define SCAN_TPB  256
#define SCAN_VPT  4                       // elements per thread
#define SCAN_TILE (SCAN_TPB * SCAN_VPT)   // 1024
#define SCAN_NBLK ((SCAN_L + SCAN_TILE - 1) / SCAN_TILE)  // 196 (<= 256)

#define NSTRIP  (N_NODES / 32)            // 625 strips of 32 rows
#define LINB    256                       // persistent blocks for k_lin / k_lin320
#define WSPLITB 2048                      // wsplit grid (grid-stride; occupancy knob)

typedef __attribute__((ext_vector_type(8))) short s16x8;   // 8 bf16 operand (4 VGPRs)
typedef __attribute__((ext_vector_type(4))) float f32x4;

static __device__ __forceinline__ float bf2f(unsigned short u) {
    union { unsigned u; float f; } x; x.u = ((unsigned)u) << 16; return x.f;
}
static __device__ __forceinline__ unsigned short f2bf(float f) {
    union { float f; unsigned u; } x; x.f = f;
    unsigned r = x.u + 0x7fffu + ((x.u >> 16) & 1u);   // RNE
    return (unsigned short)(r >> 16);
}
// split v = hi + lo (each bf16), |err| <= 2^-18 |v|
static __device__ __forceinline__ void split_bf(float v, unsigned short& h, unsigned short& l) {
    h = f2bf(v);
    l = f2bf(v - bf2f(h));
}

// ---------------- chunk-bucketed CSR build ----------------

__global__ void k_deg2(const int* __restrict__ src, const int* __restrict__ dst,
                       int* __restrict__ deg2, int e) {
    int i = blockIdx.x * 256 + threadIdx.x;
    if (i < e) {
        int s = src[i], d = dst[i];
        atomicAdd(&deg2[d * NC + (s >> CHUNK_BITS)], 1);
    }
}

// --- 3-phase multi-block exclusive scan over deg2[SCAN_L] -> ro2[0..SCAN_L] ---

__global__ __launch_bounds__(SCAN_TPB) void k_scan_part(
    const int* __restrict__ deg2, int* __restrict__ part)
{
    __shared__ int red[SCAN_TPB];
    int tid  = threadIdx.x;
    int base = blockIdx.x * SCAN_TILE + tid * SCAN_VPT;
    int s = 0;
#pragma unroll
    for (int u = 0; u < SCAN_VPT; ++u) {
        int i = base + u;
        s += (i < SCAN_L) ? deg2[i] : 0;
    }
    red[tid] = s;
    __syncthreads();
    for (int off = SCAN_TPB / 2; off > 0; off >>= 1) {
        if (tid < off) red[tid] += red[tid + off];
        __syncthreads();
    }
    if (tid == 0) part[blockIdx.x] = red[0];
}

__global__ __launch_bounds__(SCAN_TPB) void k_scan_root(int* part) {
    __shared__ int sh[SCAN_TPB];
    int tid = threadIdx.x;
    int v = (tid < SCAN_NBLK) ? part[tid] : 0;
    sh[tid] = v;
    __syncthreads();
    for (int off = 1; off < SCAN_TPB; off <<= 1) {
        int t = (tid >= off) ? sh[tid - off] : 0;
        __syncthreads();
        sh[tid] += t;
        __syncthreads();
    }
    if (tid < SCAN_NBLK) part[tid] = (tid == 0) ? 0 : sh[tid - 1];
}

__global__ __launch_bounds__(SCAN_TPB) void k_scan_write(
    const int* __restrict__ deg2, const int* __restrict__ part,
    int* __restrict__ ro2)
{
    __shared__ int red[SCAN_TPB];
    int tid  = threadIdx.x;
    int base = blockIdx.x * SCAN_TILE + tid * SCAN_VPT;
    int v[SCAN_VPT];
    int s = 0;
#pragma unroll
    for (int u = 0; u < SCAN_VPT; ++u) {
        int i = base + u;
        v[u] = (i < SCAN_L) ? deg2[i] : 0;
        s += v[u];
    }
    red[tid] = s;
    __syncthreads();
    for (int off = 1; off < SCAN_TPB; off <<= 1) {
        int t = (tid >= off) ? red[tid - off] : 0;
        __syncthreads();
        red[tid] += t;
        __syncthreads();
    }
    int excl = part[blockIdx.x] + ((tid == 0) ? 0 : red[tid - 1]);
#pragma unroll
    for (int u = 0; u < SCAN_VPT; ++u) {
        int i = base + u;
        if (i < SCAN_L) {
            ro2[i] = excl;
            excl += v[u];
            if (i == SCAN_L - 1) ro2[SCAN_L] = excl;   // total edges
        }
    }
}

__global__ void k_dinv(const int* __restrict__ ro2, float* __restrict__ dinv) {
    int n = blockIdx.x * 256 + threadIdx.x;
    if (n < N_NODES) {
        int d = ro2[(n + 1) * NC] - ro2[n * NC];
        dinv[n] = rsqrtf((float)(d + 1));   // +1 self-loop
    }
}

// packed edge record: {src, norm bits} -> one 8B load per edge
__global__ void k_scatter2(const int* __restrict__ src, const int* __restrict__ dst,
                           const int* __restrict__ ro2, int* __restrict__ cursor2,
                           const float* __restrict__ dinv,
                           int2* __restrict__ csr, int e) {
    int i = blockIdx.x * 256 + threadIdx.x;
    if (i >= e) return;
    int s = src[i], d = dst[i];
    int slot = d * NC + (s >> CHUNK_BITS);
    int pos = ro2[slot] + atomicAdd(&cursor2[slot], 1);
    float nrm = dinv[s] * dinv[d];
    csr[pos] = make_int2(s, __float_as_int(nrm));
}

// ------- batched weight transpose+split + x pre-split (1 dispatch) -------

struct WSplitArgs {
    const float* w[6];
    unsigned short* th[6];
    unsigned short* tl[6];
    const float* x;
    unsigned short* xh;
    unsigned short* xl;
};

__global__ void k_wsplit_all(WSplitArgs a) {
#pragma unroll
    for (int l = 0; l < 6; ++l) {
        const int K    = (l == 0) ? D_IN  : EMB;
        const int Kpad = (l == 0) ? KPAD0 : EMB;
        const int tot  = EMB * Kpad;
        for (int idx = blockIdx.x * 256 + threadIdx.x; idx < tot; idx += gridDim.x * 256) {
            int n = idx / Kpad, k = idx - n * Kpad;
            float v = (k < K) ? a.w[l][k * EMB + n] : 0.f;
            unsigned short h, lo;
            split_bf(v, h, lo);
            a.th[l][idx] = h; a.tl[l][idx] = lo;
        }
    }
    // x -> padded split planes [N_NODES][KPAD0]
    const int xt = N_NODES * KPAD0;
    for (int idx = blockIdx.x * 256 + threadIdx.x; idx < xt; idx += gridDim.x * 256) {
        int n = idx / KPAD0, k = idx - n * KPAD0;
        float v = (k < D_IN) ? a.x[(size_t)n * D_IN + k] : 0.f;
        unsigned short h, lo;
        split_bf(v, h, lo);
        a.xh[idx] = h; a.xl[idx] = lo;
    }
}

// ---------------- dedicated aggregation: wave-per-node, flat chunk-ordered loop ----------------
// Output written PRE-SPLIT as bf16 hi/lo planes (Ghi, Glo).

__global__ __launch_bounds__(256) void k_agg(
    const float* __restrict__ Fin,
    const int* __restrict__ ro2,
    const int2* __restrict__ csr,
    const float* __restrict__ dinv,
    const float* __restrict__ bagg,
    unsigned short* __restrict__ Ghi,
    unsigned short* __restrict__ Glo, int relu)
{
    int tid  = threadIdx.x;
    int lane = tid & 63, wave = tid >> 6;
    int node = blockIdx.x * 4 + wave;
    if (node >= N_NODES) return;

    const float4* F4 = (const float4*)Fin;
    float4 bb = *(const float4*)(bagg + lane * 4);

    float dv = dinv[node];
    float ws = dv * dv;
    float4 sv = F4[(size_t)node * 64 + lane];
    float a0 = bb.x + ws * sv.x;
    float a1 = bb.y + ws * sv.y;
    float a2 = bb.z + ws * sv.z;
    float a3 = bb.w + ws * sv.w;

    int j  = ro2[node * NC];
    int je = ro2[node * NC + NC];
    for (; j + 3 < je; j += 4) {
        int2 p0 = csr[j],     p1 = csr[j + 1];
        int2 p2 = csr[j + 2], p3 = csr[j + 3];
        float4 v0 = F4[(size_t)p0.x * 64 + lane];
        float4 v1 = F4[(size_t)p1.x * 64 + lane];
        float4 v2 = F4[(size_t)p2.x * 64 + lane];
        float4 v3 = F4[(size_t)p3.x * 64 + lane];
        float w0 = __int_as_float(p0.y), w1 = __int_as_float(p1.y);
        float w2 = __int_as_float(p2.y), w3 = __int_as_float(p3.y);
        a0 += w0 * v0.x + w1 * v1.x + w2 * v2.x + w3 * v3.x;
        a1 += w0 * v0.y + w1 * v1.y + w2 * v2.y + w3 * v3.y;
        a2 += w0 * v0.z + w1 * v1.z + w2 * v2.z + w3 * v3.z;
        a3 += w0 * v0.w + w1 * v1.w + w2 * v2.w + w3 * v3.w;
    }
    for (; j < je; ++j) {
        int2 p = csr[j];
        float w = __int_as_float(p.y);
        float4 v = F4[(size_t)p.x * 64 + lane];
        a0 += w * v.x; a1 += w * v.y; a2 += w * v.z; a3 += w * v.w;
    }

    if (relu) {
        a0 = fmaxf(a0, 0.f); a1 = fmaxf(a1, 0.f);
        a2 = fmaxf(a2, 0.f); a3 = fmaxf(a3, 0.f);
    }
    unsigned short h0, l0, h1, l1, h2, l2, h3, l3;
    split_bf(a0, h0, l0); split_bf(a1, h1, l1);
    split_bf(a2, h2, l2); split_bf(a3, h3, l3);
    ushort4 hv; hv.x = h0; hv.y = h1; hv.z = h2; hv.w = h3;
    ushort4 lv; lv.x = l0; lv.y = l1; lv.z = l2; lv.w = l3;
    *(ushort4*)(Ghi + (size_t)node * EMB + lane * 4) = hv;
    *(ushort4*)(Glo + (size_t)node * EMB + lane * 4) = lv;
}

// ---------------- persistent weight-stationary K=256 linear layer ----------------
// grid = 256 blocks (1/CU), 512 threads = 8 waves, wave owns 32 output cols.
// Weights (32 cols x 256 K, hi+lo) live in 128 VGPRs, loaded ONCE per wave.
// Blocks sweep 32-row strips (stride-256); A staged into XOR-swizzled LDS with
// a reg-staged 1-deep prefetch. MODE: 0 = f32 out (no bias); 1 = bias+relu ->
// split planes out; 2 = bias -> f32 out.

template<int MODE>
__global__ __launch_bounds__(512, 1) void k_lin(
    const unsigned short* __restrict__ Ahi,
    const unsigned short* __restrict__ Alo,
    const unsigned short* __restrict__ Wth,
    const unsigned short* __restrict__ Wtl,
    const float* __restrict__ bias,
    float* __restrict__ Cf,
    unsigned short* __restrict__ Chi,
    unsigned short* __restrict__ Clo)
{
    __shared__ unsigned short Sh[2][32][EMB];
    __shared__ unsigned short Sl[2][32][EMB];
    int tid  = threadIdx.x;
    int lane = tid & 63, wave = tid >> 6;         // 8 waves
    int quad = lane >> 4, l16 = lane & 15;

    // stationary weight fragments: wh/wl[ks][nt2]
    s16x8 wh[8][2], wl[8][2];
    {
        const unsigned short* bh = Wth + (size_t)(wave * 32 + l16) * EMB + quad * 8;
        const unsigned short* bl = Wtl + (size_t)(wave * 32 + l16) * EMB + quad * 8;
#pragma unroll
        for (int ks = 0; ks < 8; ++ks)
#pragma unroll
            for (int nt2 = 0; nt2 < 2; ++nt2) {
                wh[ks][nt2] = *(const s16x8*)(bh + (size_t)nt2 * 16 * EMB + ks * 32);
                wl[ks][nt2] = *(const s16x8*)(bl + (size_t)nt2 * 16 * EMB + ks * 32);
            }
    }
    float bb[2];
    if (MODE != 0) {
#pragma unroll
        for (int nt2 = 0; nt2 < 2; ++nt2) bb[nt2] = bias[wave * 32 + nt2 * 16 + l16];
    }

    int ns = (NSTRIP - blockIdx.x + (LINB - 1)) / LINB;   // 2 or 3 strips

    // staging map: u = tid + 512*i (i<4): plane=u>>10, row=(u>>5)&31, slot=u&31
    uint4 stg[4];
    {
        int nb0 = blockIdx.x * 32;
#pragma unroll
        for (int i = 0; i < 4; ++i) {
            int u = tid + 512 * i;
            int p = u >> 10, row = (u >> 5) & 31, s = u & 31;
            const unsigned short* srcp = (p ? Alo : Ahi) + (size_t)(nb0 + row) * EMB + s * 8;
            stg[i] = *(const uint4*)srcp;
        }
#pragma unroll
        for (int i = 0; i < 4; ++i) {
            int u = tid + 512 * i;
            int p = u >> 10, row = (u >> 5) & 31, s = u & 31;
            int sw = s ^ (row & 7);
            if (p) *(uint4*)&Sl[0][row][sw * 8] = stg[i];
            else   *(uint4*)&Sh[0][row][sw * 8] = stg[i];
        }
    }
    __syncthreads();

    for (int si = 0; si < ns; ++si) {
        int cur = si & 1;
        int nb = (blockIdx.x + si * LINB) * 32;

        // issue next strip's loads (hidden under MFMA phase)
        if (si + 1 < ns) {
            int nbn = (blockIdx.x + (si + 1) * LINB) * 32;
#pragma unroll
            for (int i = 0; i < 4; ++i) {
                int u = tid + 512 * i;
                int p = u >> 10, row = (u >> 5) & 31, s = u & 31;
                const unsigned short* srcp = (p ? Alo : Ahi) + (size_t)(nbn + row) * EMB + s * 8;
                stg[i] = *(const uint4*)srcp;
            }
        }

        f32x4 acc[2][2];
#pragma unroll
        for (int mt = 0; mt < 2; ++mt)
#pragma unroll
            for (int nt2 = 0; nt2 < 2; ++nt2) acc[mt][nt2] = (f32x4){0.f, 0.f, 0.f, 0.f};

#pragma unroll
        for (int ks = 0; ks < 8; ++ks) {
            s16x8 ah[2], al[2];
#pragma unroll
            for (int mt = 0; mt < 2; ++mt) {
                int row = mt * 16 + l16;
                int sw = (ks * 4 + quad) ^ (row & 7);
                ah[mt] = *(const s16x8*)&Sh[cur][row][sw * 8];
                al[mt] = *(const s16x8*)&Sl[cur][row][sw * 8];
            }
#pragma unroll
            for (int mt = 0; mt < 2; ++mt)
#pragma unroll
                for (int nt2 = 0; nt2 < 2; ++nt2) {
                    acc[mt][nt2] = __builtin_amdgcn_mfma_f32_16x16x32_bf16(ah[mt], wh[ks][nt2], acc[mt][nt2], 0, 0, 0);
                    acc[mt][nt2] = __builtin_amdgcn_mfma_f32_16x16x32_bf16(ah[mt], wl[ks][nt2], acc[mt][nt2], 0, 0, 0);
                    acc[mt][nt2] = __builtin_amdgcn_mfma_f32_16x16x32_bf16(al[mt], wh[ks][nt2], acc[mt][nt2], 0, 0, 0);
                }
        }

        // epilogue for strip si
#pragma unroll
        for (int mt = 0; mt < 2; ++mt)
#pragma unroll
            for (int r = 0; r < 4; ++r) {
                int row = nb + mt * 16 + quad * 4 + r;
#pragma unroll
                for (int nt2 = 0; nt2 < 2; ++nt2) {
                    int col = wave * 32 + nt2 * 16 + l16;
                    float v = acc[mt][nt2][r];
                    if (MODE == 0) {
                        Cf[(size_t)row * EMB + col] = v;
                    } else if (MODE == 1) {
                        v = fmaxf(v + bb[nt2], 0.f);
                        unsigned short h, l;
                        split_bf(v, h, l);
                        Chi[(size_t)row * EMB + col] = h;
                        Clo[(size_t)row * EMB + col] = l;
                    } else {
                        Cf[(size_t)row * EMB + col] = v + bb[nt2];
                    }
                }
            }

        // write next strip into the other LDS buffer; single barrier per strip
        if (si + 1 < ns) {
            int nxt = cur ^ 1;
#pragma unroll
            for (int i = 0; i < 4; ++i) {
                int u = tid + 512 * i;
                int p = u >> 10, row = (u >> 5) & 31, s = u & 31;
                int sw = s ^ (row & 7);
                if (p) *(uint4*)&Sl[nxt][row][sw * 8] = stg[i];
                else   *(uint4*)&Sh[nxt][row][sw * 8] = stg[i];
            }
            __syncthreads();
        }
    }
}

// ---------------- persistent weight-stationary K=320 conv0 GEMM ----------------
// Same design as k_lin but K=320 (10 ks-steps, 160 weight VGPRs), single-buffered
// 40KB LDS (static-64KB-safe), reg prefetch of next strip. f32 out, no bias.

__global__ __launch_bounds__(512, 1) void k_lin320(
    const unsigned short* __restrict__ Ahi,
    const unsigned short* __restrict__ Alo,
    const unsigned short* __restrict__ Wth,
    const unsigned short* __restrict__ Wtl,
    float* __restrict__ Cf)
{
    __shared__ unsigned short Sh[32][KPAD0];
    __shared__ unsigned short Sl[32][KPAD0];
    int tid  = threadIdx.x;
    int lane = tid & 63, wave = tid >> 6;         // 8 waves
    int quad = lane >> 4, l16 = lane & 15;

    // stationary weight fragments: wh/wl[ks][nt2], ks<10
    s16x8 wh[10][2], wl[10][2];
    {
        const unsigned short* bh = Wth + (size_t)(wave * 32 + l16) * KPAD0 + quad * 8;
        const unsigned short* bl = Wtl + (size_t)(wave * 32 + l16) * KPAD0 + quad * 8;
#pragma unroll
        for (int ks = 0; ks < 10; ++ks)
#pragma unroll
            for (int nt2 = 0; nt2 < 2; ++nt2) {
                wh[ks][nt2] = *(const s16x8*)(bh + (size_t)nt2 * 16 * KPAD0 + ks * 32);
                wl[ks][nt2] = *(const s16x8*)(bl + (size_t)nt2 * 16 * KPAD0 + ks * 32);
            }
    }

    int ns = (NSTRIP - blockIdx.x + (LINB - 1)) / LINB;

    // staging map: strip = 32 rows x 40 slots x 2 planes of uint4; 512 thr x 5
    uint4 stg[5];
    auto stage_load = [&](int nb) {
#pragma unroll
        for (int i = 0; i < 5; ++i) {
            int u = tid + 512 * i;
            int p = u / 1280, rem = u - p * 1280;
            int row = rem / 40, s = rem - row * 40;
            const unsigned short* srcp = (p ? Alo : Ahi) + (size_t)(nb + row) * KPAD0 + s * 8;
            stg[i] = *(const uint4*)srcp;
        }
    };
    auto stage_write = [&]() {
#pragma unroll
        for (int i = 0; i < 5; ++i) {
            int u = tid + 512 * i;
            int p = u / 1280, rem = u - p * 1280;
            int row = rem / 40, s = rem - row * 40;
            int sw = s ^ (row & 7);
            if (p) *(uint4*)&Sl[row][sw * 8] = stg[i];
            else   *(uint4*)&Sh[row][sw * 8] = stg[i];
        }
    };

    stage_load(blockIdx.x * 32);
    stage_write();
    __syncthreads();

    for (int si = 0; si < ns; ++si) {
        int nb = (blockIdx.x + si * LINB) * 32;

        if (si + 1 < ns) stage_load((blockIdx.x + (si + 1) * LINB) * 32);

        f32x4 acc[2][2];
#pragma unroll
        for (int mt = 0; mt < 2; ++mt)
#pragma unroll
            for (int nt2 = 0; nt2 < 2; ++nt2) acc[mt][nt2] = (f32x4){0.f, 0.f, 0.f, 0.f};

#pragma unroll
        for (int ks = 0; ks < 10; ++ks) {
            s16x8 ah[2], al[2];
#pragma unroll
            for (int mt = 0; mt < 2; ++mt) {
                int row = mt * 16 + l16;
                int sw = (ks * 4 + quad) ^ (row & 7);
                ah[mt] = *(const s16x8*)&Sh[row][sw * 8];
                al[mt] = *(const s16x8*)&Sl[row][sw * 8];
            }
#pragma unroll
            for (int mt = 0; mt < 2; ++mt)
#pragma unroll
                for (int nt2 = 0; nt2 < 2; ++nt2) {
                    acc[mt][nt2] = __builtin_amdgcn_mfma_f32_16x16x32_bf16(ah[mt], wh[ks][nt2], acc[mt][nt2], 0, 0, 0);
                    acc[mt][nt2] = __builtin_amdgcn_mfma_f32_16x16x32_bf16(ah[mt], wl[ks][nt2], acc[mt][nt2], 0, 0, 0);
                    acc[mt][nt2] = __builtin_amdgcn_mfma_f32_16x16x32_bf16(al[mt], wh[ks][nt2], acc[mt][nt2], 0, 0, 0);
                }
        }

#pragma unroll
        for (int mt = 0; mt < 2; ++mt)
#pragma unroll
            for (int r = 0; r < 4; ++r) {
                int row = nb + mt * 16 + quad * 4 + r;
#pragma unroll
                for (int nt2 = 0; nt2 < 2; ++nt2) {
                    int col = wave * 32 + nt2 * 16 + l16;
                    Cf[(size_t)row * EMB + col] = acc[mt][nt2][r];
                }
            }

        if (si + 1 < ns) {
            __syncthreads();   // all MFMA reads of LDS done
            stage_write();
            __syncthreads();
        }
    }
}

// ---------------- launch ----------------

extern "C" void kernel_launch(void* const* d_in, const int* in_sizes, int n_in,
                              void* d_out, int out_size, void* d_ws, size_t ws_size,
                              hipStream_t stream) {
    const float* x  = (const float*)d_in[0];
    const int*   ei = (const int*)d_in[1];
    const int* src = ei;
    const int* dst = ei + N_EDGES;

    const float* w[6] = {
        (const float*)d_in[2], (const float*)d_in[4], (const float*)d_in[6],
        (const float*)d_in[8], (const float*)d_in[10], (const float*)d_in[12] };
    const float* b[6] = {
        (const float*)d_in[3], (const float*)d_in[5], (const float*)d_in[7],
        (const float*)d_in[9], (const float*)d_in[11], (const float*)d_in[13] };

    char* wsp = (char*)d_ws;
    auto alloc = [&](size_t bytes) {
        char* p = wsp; wsp += (bytes + 255) & ~(size_t)255; return p;
    };
    int*   deg2     = (int*)alloc((size_t)N_NODES * NC * 4);
    int*   cursor2  = (int*)alloc((size_t)N_NODES * NC * 4);
    int*   ro2      = (int*)alloc(((size_t)N_NODES * NC + 1) * 4);
    int*   part     = (int*)alloc(SCAN_NBLK * 4);
    int2*  csr      = (int2*)alloc((size_t)N_EDGES * 8);
    float* dinv     = (float*)alloc(N_NODES * 4);
    unsigned short* wth[6];
    unsigned short* wtl[6];
    wth[0] = (unsigned short*)alloc(EMB * KPAD0 * 2);
    wtl[0] = (unsigned short*)alloc(EMB * KPAD0 * 2);
    for (int i = 1; i < 6; ++i) {
        wth[i] = (unsigned short*)alloc(EMB * EMB * 2);
        wtl[i] = (unsigned short*)alloc(EMB * EMB * 2);
    }
    unsigned short* Xhi = (unsigned short*)alloc((size_t)N_NODES * KPAD0 * 2);  // x planes
    unsigned short* Xlo = (unsigned short*)alloc((size_t)N_NODES * KPAD0 * 2);
    float* FA = (float*)alloc((size_t)N_NODES * EMB * 4);                     // f32 features
    unsigned short* Ghi = (unsigned short*)alloc((size_t)N_NODES * EMB * 2);  // plane pair A
    unsigned short* Glo = (unsigned short*)alloc((size_t)N_NODES * EMB * 2);
    unsigned short* Hhi = (unsigned short*)alloc((size_t)N_NODES * EMB * 2);  // plane pair B
    unsigned short* Hlo = (unsigned short*)alloc((size_t)N_NODES * EMB * 2);
    float* FB = (float*)d_out;                                                // d_out as scratch

    const int NB_E = (N_EDGES + 255) / 256;               // 1250
    const int NB_N = (N_NODES + 255) / 256;               // 79
    const int AB   = (N_NODES + 3) / 4;                   // 5000 (wave-per-node)

    // chunk-bucketed CSR build (multi-block scan); counter zeroing via memset
    hipMemsetAsync(deg2, 0, (size_t)N_NODES * NC * 4, stream);
    hipMemsetAsync(cursor2, 0, (size_t)N_NODES * NC * 4, stream);
    k_deg2<<<NB_E, 256, 0, stream>>>(src, dst, deg2, N_EDGES);
    k_scan_part<<<SCAN_NBLK, SCAN_TPB, 0, stream>>>(deg2, part);
    k_scan_root<<<1, SCAN_TPB, 0, stream>>>(part);
    k_scan_write<<<SCAN_NBLK, SCAN_TPB, 0, stream>>>(deg2, part, ro2);
    k_dinv<<<NB_N, 256, 0, stream>>>(ro2, dinv);
    k_scatter2<<<NB_E, 256, 0, stream>>>(src, dst, ro2, cursor2, dinv, csr, N_EDGES);

    // weights + x: transpose + hi/lo split (grid-stride; wide grid for occupancy)
    WSplitArgs wa;
    for (int i = 0; i < 6; ++i) { wa.w[i] = w[i]; wa.th[i] = wth[i]; wa.tl[i] = wtl[i]; }
    wa.x = x; wa.xh = Xhi; wa.xl = Xlo;
    k_wsplit_all<<<WSPLITB, 256, 0, stream>>>(wa);

    // conv0 gemm: x @ W0 -> FA (f32), weight-stationary persistent
    k_lin320<<<LINB, 512, 0, stream>>>(Xhi, Xlo, wth[0], wtl[0], FA);

    // conv1: agg(FA)+b0,relu -> G planes ; G @ W1 -> FB (f32)
    k_agg<<<AB, 256, 0, stream>>>(FA, ro2, csr, dinv, b[0], Ghi, Glo, 1);
    k_lin<0><<<LINB, 512, 0, stream>>>(Ghi, Glo, wth[1], wtl[1], nullptr, FB, nullptr, nullptr);

    // conv2: agg(FB)+b1,relu -> G planes ; G @ W2 -> FA (f32)
    k_agg<<<AB, 256, 0, stream>>>(FB, ro2, csr, dinv, b[1], Ghi, Glo, 1);
    k_lin<0><<<LINB, 512, 0, stream>>>(Ghi, Glo, wth[2], wtl[2], nullptr, FA, nullptr, nullptr);

    // tail: agg(FA)+b2 -> G planes ; mlp1 -> H planes ; mlp2 -> G planes ; mlp3 -> out
    k_agg<<<AB, 256, 0, stream>>>(FA, ro2, csr, dinv, b[2], Ghi, Glo, 0);
    k_lin<1><<<LINB, 512, 0, stream>>>(Ghi, Glo, wth[3], wtl[3], b[3], nullptr, Hhi, Hlo);
    k_lin<1><<<LINB, 512, 0, stream>>>(Hhi, Hlo, wth[4], wtl[4], b[4], nullptr, Ghi, Glo);
    k_lin<2><<<LINB, 512, 0, stream>>>(Ghi, Glo, wth[5], wtl[5], b[5], FB, nullptr, nullptr);
}

// Round 10
// 393.751 us; speedup vs baseline: 1.1099x; 1.0639x over previous
//
#include <hip/hip_runtime.h>
#include <stdint.h>

#define N_NODES 20000
#define N_EDGES 320000
#define EMB     256
#define D_IN    300
#define KPAD0   320   // D_IN padded to multiple of 32

// src-chunk bucketing: orders each node's edge list by src region (locality).
#define CHUNK_BITS 11
#define NC      10    // ceil(20000/2048)

// multi-block scan geometry
#define SCAN_L    (N_NODES * NC)          // 200000
#define SCAN_TPB  256
#define SCAN_VPT  4                       // elements per thread
#define SCAN_TILE (SCAN_TPB * SCAN_VPT)   // 1024
#define SCAN_NBLK ((SCAN_L + SCAN_TILE - 1) / SCAN_TILE)  // 196 (<= 256)

#define NSTRIP  (N_NODES / 32)            // 625 strips of 32 rows
#define LINB    256                       // persistent blocks for k_lin / k_lin320
#define WSPLITB 2048                      // wsplit grid (grid-stride; occupancy knob)

typedef __attribute__((ext_vector_type(8))) short s16x8;   // 8 bf16 operand (4 VGPRs)
typedef __attribute__((ext_vector_type(4))) float f32x4;

static __device__ __forceinline__ float bf2f(unsigned short u) {
    union { unsigned u; float f; } x; x.u = ((unsigned)u) << 16; return x.f;
}
static __device__ __forceinline__ unsigned short f2bf(float f) {
    union { float f; unsigned u; } x; x.f = f;
    unsigned r = x.u + 0x7fffu + ((x.u >> 16) & 1u);   // RNE
    return (unsigned short)(r >> 16);
}
// split v = hi + lo (each bf16), |err| <= 2^-18 |v|
static __device__ __forceinline__ void split_bf(float v, unsigned short& h, unsigned short& l) {
    h = f2bf(v);
    l = f2bf(v - bf2f(h));
}

// ---------------- chunk-bucketed CSR build ----------------

__global__ void k_deg2(const int* __restrict__ src, const int* __restrict__ dst,
                       int* __restrict__ deg2, int e) {
    int i = blockIdx.x * 256 + threadIdx.x;
    if (i < e) {
        int s = src[i], d = dst[i];
        atomicAdd(&deg2[d * NC + (s >> CHUNK_BITS)], 1);
    }
}

// --- 3-phase multi-block exclusive scan over deg2[SCAN_L] -> ro2[0..SCAN_L] ---

__global__ __launch_bounds__(SCAN_TPB) void k_scan_part(
    const int* __restrict__ deg2, int* __restrict__ part)
{
    __shared__ int red[SCAN_TPB];
    int tid  = threadIdx.x;
    int base = blockIdx.x * SCAN_TILE + tid * SCAN_VPT;
    int s = 0;
#pragma unroll
    for (int u = 0; u < SCAN_VPT; ++u) {
        int i = base + u;
        s += (i < SCAN_L) ? deg2[i] : 0;
    }
    red[tid] = s;
    __syncthreads();
    for (int off = SCAN_TPB / 2; off > 0; off >>= 1) {
        if (tid < off) red[tid] += red[tid + off];
        __syncthreads();
    }
    if (tid == 0) part[blockIdx.x] = red[0];
}

__global__ __launch_bounds__(SCAN_TPB) void k_scan_root(int* part) {
    __shared__ int sh[SCAN_TPB];
    int tid = threadIdx.x;
    int v = (tid < SCAN_NBLK) ? part[tid] : 0;
    sh[tid] = v;
    __syncthreads();
    for (int off = 1; off < SCAN_TPB; off <<= 1) {
        int t = (tid >= off) ? sh[tid - off] : 0;
        __syncthreads();
        sh[tid] += t;
        __syncthreads();
    }
    if (tid < SCAN_NBLK) part[tid] = (tid == 0) ? 0 : sh[tid - 1];
}

__global__ __launch_bounds__(SCAN_TPB) void k_scan_write(
    const int* __restrict__ deg2, const int* __restrict__ part,
    int* __restrict__ ro2)
{
    __shared__ int red[SCAN_TPB];
    int tid  = threadIdx.x;
    int base = blockIdx.x * SCAN_TILE + tid * SCAN_VPT;
    int v[SCAN_VPT];
    int s = 0;
#pragma unroll
    for (int u = 0; u < SCAN_VPT; ++u) {
        int i = base + u;
        v[u] = (i < SCAN_L) ? deg2[i] : 0;
        s += v[u];
    }
    red[tid] = s;
    __syncthreads();
    for (int off = 1; off < SCAN_TPB; off <<= 1) {
        int t = (tid >= off) ? red[tid - off] : 0;
        __syncthreads();
        red[tid] += t;
        __syncthreads();
    }
    int excl = part[blockIdx.x] + ((tid == 0) ? 0 : red[tid - 1]);
#pragma unroll
    for (int u = 0; u < SCAN_VPT; ++u) {
        int i = base + u;
        if (i < SCAN_L) {
            ro2[i] = excl;
            excl += v[u];
            if (i == SCAN_L - 1) ro2[SCAN_L] = excl;   // total edges
        }
    }
}

__global__ void k_dinv(const int* __restrict__ ro2, float* __restrict__ dinv) {
    int n = blockIdx.x * 256 + threadIdx.x;
    if (n < N_NODES) {
        int d = ro2[(n + 1) * NC] - ro2[n * NC];
        dinv[n] = rsqrtf((float)(d + 1));   // +1 self-loop
    }
}

// packed edge record: {src, norm bits} -> one 8B load per edge
__global__ void k_scatter2(const int* __restrict__ src, const int* __restrict__ dst,
                           const int* __restrict__ ro2, int* __restrict__ cursor2,
                           const float* __restrict__ dinv,
                           int2* __restrict__ csr, int e) {
    int i = blockIdx.x * 256 + threadIdx.x;
    if (i >= e) return;
    int s = src[i], d = dst[i];
    int slot = d * NC + (s >> CHUNK_BITS);
    int pos = ro2[slot] + atomicAdd(&cursor2[slot], 1);
    float nrm = dinv[s] * dinv[d];
    csr[pos] = make_int2(s, __float_as_int(nrm));
}

// ------- batched weight transpose+split + x pre-split (1 dispatch) -------

struct WSplitArgs {
    const float* w[6];
    unsigned short* th[6];
    unsigned short* tl[6];
    const float* x;
    unsigned short* xh;
    unsigned short* xl;
};

__global__ void k_wsplit_all(WSplitArgs a) {
#pragma unroll
    for (int l = 0; l < 6; ++l) {
        const int K    = (l == 0) ? D_IN  : EMB;
        const int Kpad = (l == 0) ? KPAD0 : EMB;
        const int tot  = EMB * Kpad;
        for (int idx = blockIdx.x * 256 + threadIdx.x; idx < tot; idx += gridDim.x * 256) {
            int n = idx / Kpad, k = idx - n * Kpad;
            float v = (k < K) ? a.w[l][k * EMB + n] : 0.f;
            unsigned short h, lo;
            split_bf(v, h, lo);
            a.th[l][idx] = h; a.tl[l][idx] = lo;
        }
    }
    // x -> padded split planes [N_NODES][KPAD0]
    const int xt = N_NODES * KPAD0;
    for (int idx = blockIdx.x * 256 + threadIdx.x; idx < xt; idx += gridDim.x * 256) {
        int n = idx / KPAD0, k = idx - n * KPAD0;
        float v = (k < D_IN) ? a.x[(size_t)n * D_IN + k] : 0.f;
        unsigned short h, lo;
        split_bf(v, h, lo);
        a.xh[idx] = h; a.xl[idx] = lo;
    }
}

// ---------------- XCD-dim-sliced aggregation ----------------
// Block owns dim-group g = blockIdx&7 (32 dims, 128B/row); under round-robin
// block->XCD mapping, XCD x only ever reads F[:, x*32..x*32+32) = 2.5MB ->
// L2-resident, killing the 8x cross-XCD fill duplication (was FETCH=139MB).
// Wave: 8 nodes in parallel, 8 lanes/node (li = lane&7 -> dims li*4..li*4+4).
// Edge order per node identical to before -> bitwise-identical results.

__global__ __launch_bounds__(256) void k_agg(
    const float* __restrict__ Fin,
    const int* __restrict__ ro2,
    const int2* __restrict__ csr,
    const float* __restrict__ dinv,
    const float* __restrict__ bagg,
    unsigned short* __restrict__ Ghi,
    unsigned short* __restrict__ Glo, int relu)
{
    int tid   = threadIdx.x;
    int lane  = tid & 63, wave = tid >> 6;
    int g     = blockIdx.x & 7;           // dim-group -> XCD (round-robin heuristic)
    int strip = blockIdx.x >> 3;
    int sub   = lane >> 3, li = lane & 7;
    int node  = strip * 32 + wave * 8 + sub;

    const float4* F4 = (const float4*)Fin;
    int fo = g * 8 + li;                  // float4 index within the 64-float4 row
    float4 bb = *(const float4*)(bagg + g * 32 + li * 4);

    float dv = dinv[node];
    float ws = dv * dv;
    float4 sv = F4[(size_t)node * 64 + fo];
    float a0 = bb.x + ws * sv.x;
    float a1 = bb.y + ws * sv.y;
    float a2 = bb.z + ws * sv.z;
    float a3 = bb.w + ws * sv.w;

    int j  = ro2[node * NC];
    int je = ro2[node * NC + NC];
    for (; j + 3 < je; j += 4) {
        int2 p0 = csr[j],     p1 = csr[j + 1];
        int2 p2 = csr[j + 2], p3 = csr[j + 3];
        float4 v0 = F4[(size_t)p0.x * 64 + fo];
        float4 v1 = F4[(size_t)p1.x * 64 + fo];
        float4 v2 = F4[(size_t)p2.x * 64 + fo];
        float4 v3 = F4[(size_t)p3.x * 64 + fo];
        float w0 = __int_as_float(p0.y), w1 = __int_as_float(p1.y);
        float w2 = __int_as_float(p2.y), w3 = __int_as_float(p3.y);
        a0 += w0 * v0.x + w1 * v1.x + w2 * v2.x + w3 * v3.x;
        a1 += w0 * v0.y + w1 * v1.y + w2 * v2.y + w3 * v3.y;
        a2 += w0 * v0.z + w1 * v1.z + w2 * v2.z + w3 * v3.z;
        a3 += w0 * v0.w + w1 * v1.w + w2 * v2.w + w3 * v3.w;
    }
    for (; j < je; ++j) {
        int2 p = csr[j];
        float w = __int_as_float(p.y);
        float4 v = F4[(size_t)p.x * 64 + fo];
        a0 += w * v.x; a1 += w * v.y; a2 += w * v.z; a3 += w * v.w;
    }

    if (relu) {
        a0 = fmaxf(a0, 0.f); a1 = fmaxf(a1, 0.f);
        a2 = fmaxf(a2, 0.f); a3 = fmaxf(a3, 0.f);
    }
    unsigned short h0, l0, h1, l1, h2, l2, h3, l3;
    split_bf(a0, h0, l0); split_bf(a1, h1, l1);
    split_bf(a2, h2, l2); split_bf(a3, h3, l3);
    ushort4 hv; hv.x = h0; hv.y = h1; hv.z = h2; hv.w = h3;
    ushort4 lv; lv.x = l0; lv.y = l1; lv.z = l2; lv.w = l3;
    size_t off = (size_t)node * EMB + g * 32 + li * 4;
    *(ushort4*)(Ghi + off) = hv;
    *(ushort4*)(Glo + off) = lv;
}

// ---------------- persistent weight-stationary K=256 linear layer ----------------
// grid = 256 blocks (1/CU), 512 threads = 8 waves, wave owns 32 output cols.
// Weights (32 cols x 256 K, hi+lo) live in 128 VGPRs, loaded ONCE per wave.
// Blocks sweep 32-row strips (stride-256); A staged into XOR-swizzled LDS with
// a reg-staged 1-deep prefetch. MODE: 0 = f32 out (no bias); 1 = bias+relu ->
// split planes out; 2 = bias -> f32 out.

template<int MODE>
__global__ __launch_bounds__(512, 1) void k_lin(
    const unsigned short* __restrict__ Ahi,
    const unsigned short* __restrict__ Alo,
    const unsigned short* __restrict__ Wth,
    const unsigned short* __restrict__ Wtl,
    const float* __restrict__ bias,
    float* __restrict__ Cf,
    unsigned short* __restrict__ Chi,
    unsigned short* __restrict__ Clo)
{
    __shared__ unsigned short Sh[2][32][EMB];
    __shared__ unsigned short Sl[2][32][EMB];
    int tid  = threadIdx.x;
    int lane = tid & 63, wave = tid >> 6;         // 8 waves
    int quad = lane >> 4, l16 = lane & 15;

    // stationary weight fragments: wh/wl[ks][nt2]
    s16x8 wh[8][2], wl[8][2];
    {
        const unsigned short* bh = Wth + (size_t)(wave * 32 + l16) * EMB + quad * 8;
        const unsigned short* bl = Wtl + (size_t)(wave * 32 + l16) * EMB + quad * 8;
#pragma unroll
        for (int ks = 0; ks < 8; ++ks)
#pragma unroll
            for (int nt2 = 0; nt2 < 2; ++nt2) {
                wh[ks][nt2] = *(const s16x8*)(bh + (size_t)nt2 * 16 * EMB + ks * 32);
                wl[ks][nt2] = *(const s16x8*)(bl + (size_t)nt2 * 16 * EMB + ks * 32);
            }
    }
    float bb[2];
    if (MODE != 0) {
#pragma unroll
        for (int nt2 = 0; nt2 < 2; ++nt2) bb[nt2] = bias[wave * 32 + nt2 * 16 + l16];
    }

    int ns = (NSTRIP - blockIdx.x + (LINB - 1)) / LINB;   // 2 or 3 strips

    // staging map: u = tid + 512*i (i<4): plane=u>>10, row=(u>>5)&31, slot=u&31
    uint4 stg[4];
    {
        int nb0 = blockIdx.x * 32;
#pragma unroll
        for (int i = 0; i < 4; ++i) {
            int u = tid + 512 * i;
            int p = u >> 10, row = (u >> 5) & 31, s = u & 31;
            const unsigned short* srcp = (p ? Alo : Ahi) + (size_t)(nb0 + row) * EMB + s * 8;
            stg[i] = *(const uint4*)srcp;
        }
#pragma unroll
        for (int i = 0; i < 4; ++i) {
            int u = tid + 512 * i;
            int p = u >> 10, row = (u >> 5) & 31, s = u & 31;
            int sw = s ^ (row & 7);
            if (p) *(uint4*)&Sl[0][row][sw * 8] = stg[i];
            else   *(uint4*)&Sh[0][row][sw * 8] = stg[i];
        }
    }
    __syncthreads();

    for (int si = 0; si < ns; ++si) {
        int cur = si & 1;
        int nb = (blockIdx.x + si * LINB) * 32;

        // issue next strip's loads (hidden under MFMA phase)
        if (si + 1 < ns) {
            int nbn = (blockIdx.x + (si + 1) * LINB) * 32;
#pragma unroll
            for (int i = 0; i < 4; ++i) {
                int u = tid + 512 * i;
                int p = u >> 10, row = (u >> 5) & 31, s = u & 31;
                const unsigned short* srcp = (p ? Alo : Ahi) + (size_t)(nbn + row) * EMB + s * 8;
                stg[i] = *(const uint4*)srcp;
            }
        }

        f32x4 acc[2][2];
#pragma unroll
        for (int mt = 0; mt < 2; ++mt)
#pragma unroll
            for (int nt2 = 0; nt2 < 2; ++nt2) acc[mt][nt2] = (f32x4){0.f, 0.f, 0.f, 0.f};

#pragma unroll
        for (int ks = 0; ks < 8; ++ks) {
            s16x8 ah[2], al[2];
#pragma unroll
            for (int mt = 0; mt < 2; ++mt) {
                int row = mt * 16 + l16;
                int sw = (ks * 4 + quad) ^ (row & 7);
                ah[mt] = *(const s16x8*)&Sh[cur][row][sw * 8];
                al[mt] = *(const s16x8*)&Sl[cur][row][sw * 8];
            }
#pragma unroll
            for (int mt = 0; mt < 2; ++mt)
#pragma unroll
                for (int nt2 = 0; nt2 < 2; ++nt2) {
                    acc[mt][nt2] = __builtin_amdgcn_mfma_f32_16x16x32_bf16(ah[mt], wh[ks][nt2], acc[mt][nt2], 0, 0, 0);
                    acc[mt][nt2] = __builtin_amdgcn_mfma_f32_16x16x32_bf16(ah[mt], wl[ks][nt2], acc[mt][nt2], 0, 0, 0);
                    acc[mt][nt2] = __builtin_amdgcn_mfma_f32_16x16x32_bf16(al[mt], wh[ks][nt2], acc[mt][nt2], 0, 0, 0);
                }
        }

        // epilogue for strip si
#pragma unroll
        for (int mt = 0; mt < 2; ++mt)
#pragma unroll
            for (int r = 0; r < 4; ++r) {
                int row = nb + mt * 16 + quad * 4 + r;
#pragma unroll
                for (int nt2 = 0; nt2 < 2; ++nt2) {
                    int col = wave * 32 + nt2 * 16 + l16;
                    float v = acc[mt][nt2][r];
                    if (MODE == 0) {
                        Cf[(size_t)row * EMB + col] = v;
                    } else if (MODE == 1) {
                        v = fmaxf(v + bb[nt2], 0.f);
                        unsigned short h, l;
                        split_bf(v, h, l);
                        Chi[(size_t)row * EMB + col] = h;
                        Clo[(size_t)row * EMB + col] = l;
                    } else {
                        Cf[(size_t)row * EMB + col] = v + bb[nt2];
                    }
                }
            }

        // write next strip into the other LDS buffer; single barrier per strip
        if (si + 1 < ns) {
            int nxt = cur ^ 1;
#pragma unroll
            for (int i = 0; i < 4; ++i) {
                int u = tid + 512 * i;
                int p = u >> 10, row = (u >> 5) & 31, s = u & 31;
                int sw = s ^ (row & 7);
                if (p) *(uint4*)&Sl[nxt][row][sw * 8] = stg[i];
                else   *(uint4*)&Sh[nxt][row][sw * 8] = stg[i];
            }
            __syncthreads();
        }
    }
}

// ---------------- persistent weight-stationary K=320 conv0 GEMM ----------------
// Same design as k_lin but K=320 (10 ks-steps, 160 weight VGPRs), single-buffered
// 40KB LDS (static-64KB-safe), reg prefetch of next strip. f32 out, no bias.

__global__ __launch_bounds__(512, 1) void k_lin320(
    const unsigned short* __restrict__ Ahi,
    const unsigned short* __restrict__ Alo,
    const unsigned short* __restrict__ Wth,
    const unsigned short* __restrict__ Wtl,
    float* __restrict__ Cf)
{
    __shared__ unsigned short Sh[32][KPAD0];
    __shared__ unsigned short Sl[32][KPAD0];
    int tid  = threadIdx.x;
    int lane = tid & 63, wave = tid >> 6;         // 8 waves
    int quad = lane >> 4, l16 = lane & 15;

    // stationary weight fragments: wh/wl[ks][nt2], ks<10
    s16x8 wh[10][2], wl[10][2];
    {
        const unsigned short* bh = Wth + (size_t)(wave * 32 + l16) * KPAD0 + quad * 8;
        const unsigned short* bl = Wtl + (size_t)(wave * 32 + l16) * KPAD0 + quad * 8;
#pragma unroll
        for (int ks = 0; ks < 10; ++ks)
#pragma unroll
            for (int nt2 = 0; nt2 < 2; ++nt2) {
                wh[ks][nt2] = *(const s16x8*)(bh + (size_t)nt2 * 16 * KPAD0 + ks * 32);
                wl[ks][nt2] = *(const s16x8*)(bl + (size_t)nt2 * 16 * KPAD0 + ks * 32);
            }
    }

    int ns = (NSTRIP - blockIdx.x + (LINB - 1)) / LINB;

    // staging map: strip = 32 rows x 40 slots x 2 planes of uint4; 512 thr x 5
    uint4 stg[5];
    auto stage_load = [&](int nb) {
#pragma unroll
        for (int i = 0; i < 5; ++i) {
            int u = tid + 512 * i;
            int p = u / 1280, rem = u - p * 1280;
            int row = rem / 40, s = rem - row * 40;
            const unsigned short* srcp = (p ? Alo : Ahi) + (size_t)(nb + row) * KPAD0 + s * 8;
            stg[i] = *(const uint4*)srcp;
        }
    };
    auto stage_write = [&]() {
#pragma unroll
        for (int i = 0; i < 5; ++i) {
            int u = tid + 512 * i;
            int p = u / 1280, rem = u - p * 1280;
            int row = rem / 40, s = rem - row * 40;
            int sw = s ^ (row & 7);
            if (p) *(uint4*)&Sl[row][sw * 8] = stg[i];
            else   *(uint4*)&Sh[row][sw * 8] = stg[i];
        }
    };

    stage_load(blockIdx.x * 32);
    stage_write();
    __syncthreads();

    for (int si = 0; si < ns; ++si) {
        int nb = (blockIdx.x + si * LINB) * 32;

        if (si + 1 < ns) stage_load((blockIdx.x + (si + 1) * LINB) * 32);

        f32x4 acc[2][2];
#pragma unroll
        for (int mt = 0; mt < 2; ++mt)
#pragma unroll
            for (int nt2 = 0; nt2 < 2; ++nt2) acc[mt][nt2] = (f32x4){0.f, 0.f, 0.f, 0.f};

#pragma unroll
        for (int ks = 0; ks < 10; ++ks) {
            s16x8 ah[2], al[2];
#pragma unroll
            for (int mt = 0; mt < 2; ++mt) {
                int row = mt * 16 + l16;
                int sw = (ks * 4 + quad) ^ (row & 7);
                ah[mt] = *(const s16x8*)&Sh[row][sw * 8];
                al[mt] = *(const s16x8*)&Sl[row][sw * 8];
            }
#pragma unroll
            for (int mt = 0; mt < 2; ++mt)
#pragma unroll
                for (int nt2 = 0; nt2 < 2; ++nt2) {
                    acc[mt][nt2] = __builtin_amdgcn_mfma_f32_16x16x32_bf16(ah[mt], wh[ks][nt2], acc[mt][nt2], 0, 0, 0);
                    acc[mt][nt2] = __builtin_amdgcn_mfma_f32_16x16x32_bf16(ah[mt], wl[ks][nt2], acc[mt][nt2], 0, 0, 0);
                    acc[mt][nt2] = __builtin_amdgcn_mfma_f32_16x16x32_bf16(al[mt], wh[ks][nt2], acc[mt][nt2], 0, 0, 0);
                }
        }

#pragma unroll
        for (int mt = 0; mt < 2; ++mt)
#pragma unroll
            for (int r = 0; r < 4; ++r) {
                int row = nb + mt * 16 + quad * 4 + r;
#pragma unroll
                for (int nt2 = 0; nt2 < 2; ++nt2) {
                    int col = wave * 32 + nt2 * 16 + l16;
                    Cf[(size_t)row * EMB + col] = acc[mt][nt2][r];
                }
            }

        if (si + 1 < ns) {
            __syncthreads();   // all MFMA reads of LDS done
            stage_write();
            __syncthreads();
        }
    }
}

// ---------------- launch ----------------

extern "C" void kernel_launch(void* const* d_in, const int* in_sizes, int n_in,
                              void* d_out, int out_size, void* d_ws, size_t ws_size,
                              hipStream_t stream) {
    const float* x  = (const float*)d_in[0];
    const int*   ei = (const int*)d_in[1];
    const int* src = ei;
    const int* dst = ei + N_EDGES;

    const float* w[6] = {
        (const float*)d_in[2], (const float*)d_in[4], (const float*)d_in[6],
        (const float*)d_in[8], (const float*)d_in[10], (const float*)d_in[12] };
    const float* b[6] = {
        (const float*)d_in[3], (const float*)d_in[5], (const float*)d_in[7],
        (const float*)d_in[9], (const float*)d_in[11], (const float*)d_in[13] };

    char* wsp = (char*)d_ws;
    auto alloc = [&](size_t bytes) {
        char* p = wsp; wsp += (bytes + 255) & ~(size_t)255; return p;
    };
    int*   deg2     = (int*)alloc((size_t)N_NODES * NC * 4);
    int*   cursor2  = (int*)alloc((size_t)N_NODES * NC * 4);
    int*   ro2      = (int*)alloc(((size_t)N_NODES * NC + 1) * 4);
    int*   part     = (int*)alloc(SCAN_NBLK * 4);
    int2*  csr      = (int2*)alloc((size_t)N_EDGES * 8);
    float* dinv     = (float*)alloc(N_NODES * 4);
    unsigned short* wth[6];
    unsigned short* wtl[6];
    wth[0] = (unsigned short*)alloc(EMB * KPAD0 * 2);
    wtl[0] = (unsigned short*)alloc(EMB * KPAD0 * 2);
    for (int i = 1; i < 6; ++i) {
        wth[i] = (unsigned short*)alloc(EMB * EMB * 2);
        wtl[i] = (unsigned short*)alloc(EMB * EMB * 2);
    }
    unsigned short* Xhi = (unsigned short*)alloc((size_t)N_NODES * KPAD0 * 2);  // x planes
    unsigned short* Xlo = (unsigned short*)alloc((size_t)N_NODES * KPAD0 * 2);
    float* FA = (float*)alloc((size_t)N_NODES * EMB * 4);                     // f32 features
    unsigned short* Ghi = (unsigned short*)alloc((size_t)N_NODES * EMB * 2);  // plane pair A
    unsigned short* Glo = (unsigned short*)alloc((size_t)N_NODES * EMB * 2);
    unsigned short* Hhi = (unsigned short*)alloc((size_t)N_NODES * EMB * 2);  // plane pair B
    unsigned short* Hlo = (unsigned short*)alloc((size_t)N_NODES * EMB * 2);
    float* FB = (float*)d_out;                                                // d_out as scratch

    const int NB_E = (N_EDGES + 255) / 256;               // 1250
    const int NB_N = (N_NODES + 255) / 256;               // 79
    const int ABX  = NSTRIP * 8;                          // 5000 (strip x dim-group)

    // chunk-bucketed CSR build (multi-block scan); counter zeroing via memset
    hipMemsetAsync(deg2, 0, (size_t)N_NODES * NC * 4, stream);
    hipMemsetAsync(cursor2, 0, (size_t)N_NODES * NC * 4, stream);
    k_deg2<<<NB_E, 256, 0, stream>>>(src, dst, deg2, N_EDGES);
    k_scan_part<<<SCAN_NBLK, SCAN_TPB, 0, stream>>>(deg2, part);
    k_scan_root<<<1, SCAN_TPB, 0, stream>>>(part);
    k_scan_write<<<SCAN_NBLK, SCAN_TPB, 0, stream>>>(deg2, part, ro2);
    k_dinv<<<NB_N, 256, 0, stream>>>(ro2, dinv);
    k_scatter2<<<NB_E, 256, 0, stream>>>(src, dst, ro2, cursor2, dinv, csr, N_EDGES);

    // weights + x: transpose + hi/lo split (grid-stride; wide grid for occupancy)
    WSplitArgs wa;
    for (int i = 0; i < 6; ++i) { wa.w[i] = w[i]; wa.th[i] = wth[i]; wa.tl[i] = wtl[i]; }
    wa.x = x; wa.xh = Xhi; wa.xl = Xlo;
    k_wsplit_all<<<WSPLITB, 256, 0, stream>>>(wa);

    // conv0 gemm: x @ W0 -> FA (f32), weight-stationary persistent
    k_lin320<<<LINB, 512, 0, stream>>>(Xhi, Xlo, wth[0], wtl[0], FA);

    // conv1: agg(FA)+b0,relu -> G planes ; G @ W1 -> FB (f32)
    k_agg<<<ABX, 256, 0, stream>>>(FA, ro2, csr, dinv, b[0], Ghi, Glo, 1);
    k_lin<0><<<LINB, 512, 0, stream>>>(Ghi, Glo, wth[1], wtl[1], nullptr, FB, nullptr, nullptr);

    // conv2: agg(FB)+b1,relu -> G planes ; G @ W2 -> FA (f32)
    k_agg<<<ABX, 256, 0, stream>>>(FB, ro2, csr, dinv, b[1], Ghi, Glo, 1);
    k_lin<0><<<LINB, 512, 0, stream>>>(Ghi, Glo, wth[2], wtl[2], nullptr, FA, nullptr, nullptr);

    // tail: agg(FA)+b2 -> G planes ; mlp1 -> H planes ; mlp2 -> G planes ; mlp3 -> out
    k_agg<<<ABX, 256, 0, stream>>>(FA, ro2, csr, dinv, b[2], Ghi, Glo, 0);
    k_lin<1><<<LINB, 512, 0, stream>>>(Ghi, Glo, wth[3], wtl[3], b[3], nullptr, Hhi, Hlo);
    k_lin<1><<<LINB, 512, 0, stream>>>(Hhi, Hlo, wth[4], wtl[4], b[4], nullptr, Ghi, Glo);
    k_lin<2><<<LINB, 512, 0, stream>>>(Ghi, Glo, wth[5], wtl[5], b[5], FB, nullptr, nullptr);
}

// Round 11
// 388.431 us; speedup vs baseline: 1.1251x; 1.0137x over previous
//
#include <hip/hip_runtime.h>
#include <stdint.h>

#define N_NODES 20000
#define N_EDGES 320000
#define EMB     256
#define D_IN    300
#define KPAD0   320   // D_IN padded to multiple of 32

// multi-block scan geometry (simple per-node CSR, NC=1)
#define SCAN_L    N_NODES                 // 20000
#define SCAN_TPB  256
#define SCAN_VPT  4                       // elements per thread
#define SCAN_TILE (SCAN_TPB * SCAN_VPT)   // 1024
#define SCAN_NBLK ((SCAN_L + SCAN_TILE - 1) / SCAN_TILE)  // 20

#define NSTRIP  (N_NODES / 32)            // 625 strips of 32 rows
#define LINB    256                       // persistent blocks for k_lin / k_lin320
#define WSPLITB 1024                      // wsplit grid (grid-stride)

typedef __attribute__((ext_vector_type(8))) short s16x8;   // 8 bf16 operand (4 VGPRs)
typedef __attribute__((ext_vector_type(4))) float f32x4;

static __device__ __forceinline__ float bf2f(unsigned short u) {
    union { unsigned u; float f; } x; x.u = ((unsigned)u) << 16; return x.f;
}
static __device__ __forceinline__ unsigned short f2bf(float f) {
    union { float f; unsigned u; } x; x.f = f;
    unsigned r = x.u + 0x7fffu + ((x.u >> 16) & 1u);   // RNE
    return (unsigned short)(r >> 16);
}
// split v = hi + lo (each bf16), |err| <= 2^-18 |v|
static __device__ __forceinline__ void split_bf(float v, unsigned short& h, unsigned short& l) {
    h = f2bf(v);
    l = f2bf(v - bf2f(h));
}

// ---------------- per-node CSR build ----------------

__global__ void k_deg(const int* __restrict__ dst, int* __restrict__ deg, int e) {
    int i = blockIdx.x * 256 + threadIdx.x;
    if (i < e) atomicAdd(&deg[dst[i]], 1);
}

// --- 3-phase multi-block exclusive scan over deg[20000] -> ro[0..20000] + dinv ---

__global__ __launch_bounds__(SCAN_TPB) void k_scan_part(
    const int* __restrict__ deg, int* __restrict__ part)
{
    __shared__ int red[SCAN_TPB];
    int tid  = threadIdx.x;
    int base = blockIdx.x * SCAN_TILE + tid * SCAN_VPT;
    int s = 0;
#pragma unroll
    for (int u = 0; u < SCAN_VPT; ++u) {
        int i = base + u;
        s += (i < SCAN_L) ? deg[i] : 0;
    }
    red[tid] = s;
    __syncthreads();
    for (int off = SCAN_TPB / 2; off > 0; off >>= 1) {
        if (tid < off) red[tid] += red[tid + off];
        __syncthreads();
    }
    if (tid == 0) part[blockIdx.x] = red[0];
}

__global__ __launch_bounds__(SCAN_TPB) void k_scan_root(int* part) {
    __shared__ int sh[SCAN_TPB];
    int tid = threadIdx.x;
    int v = (tid < SCAN_NBLK) ? part[tid] : 0;
    sh[tid] = v;
    __syncthreads();
    for (int off = 1; off < SCAN_TPB; off <<= 1) {
        int t = (tid >= off) ? sh[tid - off] : 0;
        __syncthreads();
        sh[tid] += t;
        __syncthreads();
    }
    if (tid < SCAN_NBLK) part[tid] = (tid == 0) ? 0 : sh[tid - 1];
}

// scan-write + dinv (fused: deg value is the node degree since NC=1)
__global__ __launch_bounds__(SCAN_TPB) void k_scan_write(
    const int* __restrict__ deg, const int* __restrict__ part,
    int* __restrict__ ro, float* __restrict__ dinv)
{
    __shared__ int red[SCAN_TPB];
    int tid  = threadIdx.x;
    int base = blockIdx.x * SCAN_TILE + tid * SCAN_VPT;
    int v[SCAN_VPT];
    int s = 0;
#pragma unroll
    for (int u = 0; u < SCAN_VPT; ++u) {
        int i = base + u;
        v[u] = (i < SCAN_L) ? deg[i] : 0;
        s += v[u];
    }
    red[tid] = s;
    __syncthreads();
    for (int off = 1; off < SCAN_TPB; off <<= 1) {
        int t = (tid >= off) ? red[tid - off] : 0;
        __syncthreads();
        red[tid] += t;
        __syncthreads();
    }
    int excl = part[blockIdx.x] + ((tid == 0) ? 0 : red[tid - 1]);
#pragma unroll
    for (int u = 0; u < SCAN_VPT; ++u) {
        int i = base + u;
        if (i < SCAN_L) {
            ro[i] = excl;
            dinv[i] = rsqrtf((float)(v[u] + 1));   // +1 self-loop
            excl += v[u];
            if (i == SCAN_L - 1) ro[SCAN_L] = excl;   // total edges
        }
    }
}

// packed edge record: {src, norm bits} -> one 8B load per edge
__global__ void k_scatter(const int* __restrict__ src, const int* __restrict__ dst,
                          const int* __restrict__ ro, int* __restrict__ cursor,
                          const float* __restrict__ dinv,
                          int2* __restrict__ csr, int e) {
    int i = blockIdx.x * 256 + threadIdx.x;
    if (i >= e) return;
    int s = src[i], d = dst[i];
    int pos = ro[d] + atomicAdd(&cursor[d], 1);
    float nrm = dinv[s] * dinv[d];
    csr[pos] = make_int2(s, __float_as_int(nrm));
}

// ------- batched weight transpose+split (weights only; 1 dispatch) -------

struct WSplitArgs {
    const float* w[6];
    unsigned short* th[6];
    unsigned short* tl[6];
};

__global__ void k_wsplit_all(WSplitArgs a) {
#pragma unroll
    for (int l = 0; l < 6; ++l) {
        const int K    = (l == 0) ? D_IN  : EMB;
        const int Kpad = (l == 0) ? KPAD0 : EMB;
        const int tot  = EMB * Kpad;
        for (int idx = blockIdx.x * 256 + threadIdx.x; idx < tot; idx += gridDim.x * 256) {
            int n = idx / Kpad, k = idx - n * Kpad;
            float v = (k < K) ? a.w[l][k * EMB + n] : 0.f;
            unsigned short h, lo;
            split_bf(v, h, lo);
            a.th[l][idx] = h; a.tl[l][idx] = lo;
        }
    }
}

// ---------------- XCD-dim-sliced aggregation ----------------
// Block owns dim-group g = blockIdx&7 (32 dims, 128B/row); under round-robin
// block->XCD mapping, XCD x only ever reads F[:, x*32..x*32+32) = 2.5MB ->
// L2-resident, killing the 8x cross-XCD fill duplication.
// Wave: 8 nodes in parallel, 8 lanes/node (li = lane&7 -> dims li*4..li*4+4).

__global__ __launch_bounds__(256) void k_agg(
    const float* __restrict__ Fin,
    const int* __restrict__ ro,
    const int2* __restrict__ csr,
    const float* __restrict__ dinv,
    const float* __restrict__ bagg,
    unsigned short* __restrict__ Ghi,
    unsigned short* __restrict__ Glo, int relu)
{
    int tid   = threadIdx.x;
    int lane  = tid & 63, wave = tid >> 6;
    int g     = blockIdx.x & 7;           // dim-group -> XCD (round-robin heuristic)
    int strip = blockIdx.x >> 3;
    int sub   = lane >> 3, li = lane & 7;
    int node  = strip * 32 + wave * 8 + sub;

    const float4* F4 = (const float4*)Fin;
    int fo = g * 8 + li;                  // float4 index within the 64-float4 row
    float4 bb = *(const float4*)(bagg + g * 32 + li * 4);

    float dv = dinv[node];
    float ws = dv * dv;
    float4 sv = F4[(size_t)node * 64 + fo];
    float a0 = bb.x + ws * sv.x;
    float a1 = bb.y + ws * sv.y;
    float a2 = bb.z + ws * sv.z;
    float a3 = bb.w + ws * sv.w;

    int j  = ro[node];
    int je = ro[node + 1];
    for (; j + 3 < je; j += 4) {
        int2 p0 = csr[j],     p1 = csr[j + 1];
        int2 p2 = csr[j + 2], p3 = csr[j + 3];
        float4 v0 = F4[(size_t)p0.x * 64 + fo];
        float4 v1 = F4[(size_t)p1.x * 64 + fo];
        float4 v2 = F4[(size_t)p2.x * 64 + fo];
        float4 v3 = F4[(size_t)p3.x * 64 + fo];
        float w0 = __int_as_float(p0.y), w1 = __int_as_float(p1.y);
        float w2 = __int_as_float(p2.y), w3 = __int_as_float(p3.y);
        a0 += w0 * v0.x + w1 * v1.x + w2 * v2.x + w3 * v3.x;
        a1 += w0 * v0.y + w1 * v1.y + w2 * v2.y + w3 * v3.y;
        a2 += w0 * v0.z + w1 * v1.z + w2 * v2.z + w3 * v3.z;
        a3 += w0 * v0.w + w1 * v1.w + w2 * v2.w + w3 * v3.w;
    }
    for (; j < je; ++j) {
        int2 p = csr[j];
        float w = __int_as_float(p.y);
        float4 v = F4[(size_t)p.x * 64 + fo];
        a0 += w * v.x; a1 += w * v.y; a2 += w * v.z; a3 += w * v.w;
    }

    if (relu) {
        a0 = fmaxf(a0, 0.f); a1 = fmaxf(a1, 0.f);
        a2 = fmaxf(a2, 0.f); a3 = fmaxf(a3, 0.f);
    }
    unsigned short h0, l0, h1, l1, h2, l2, h3, l3;
    split_bf(a0, h0, l0); split_bf(a1, h1, l1);
    split_bf(a2, h2, l2); split_bf(a3, h3, l3);
    ushort4 hv; hv.x = h0; hv.y = h1; hv.z = h2; hv.w = h3;
    ushort4 lv; lv.x = l0; lv.y = l1; lv.z = l2; lv.w = l3;
    size_t off = (size_t)node * EMB + g * 32 + li * 4;
    *(ushort4*)(Ghi + off) = hv;
    *(ushort4*)(Glo + off) = lv;
}

// ---------------- persistent weight-stationary K=256 linear layer ----------------
// grid = 256 blocks (1/CU), 512 threads = 8 waves, wave owns 32 output cols.
// Weights (32 cols x 256 K, hi+lo) live in 128 VGPRs, loaded ONCE per wave.
// Blocks sweep 32-row strips (stride-256); A staged into XOR-swizzled LDS with
// a reg-staged 1-deep prefetch. MODE: 0 = f32 out (no bias); 1 = bias+relu ->
// split planes out; 2 = bias -> f32 out.

template<int MODE>
__global__ __launch_bounds__(512, 1) void k_lin(
    const unsigned short* __restrict__ Ahi,
    const unsigned short* __restrict__ Alo,
    const unsigned short* __restrict__ Wth,
    const unsigned short* __restrict__ Wtl,
    const float* __restrict__ bias,
    float* __restrict__ Cf,
    unsigned short* __restrict__ Chi,
    unsigned short* __restrict__ Clo)
{
    __shared__ unsigned short Sh[2][32][EMB];
    __shared__ unsigned short Sl[2][32][EMB];
    int tid  = threadIdx.x;
    int lane = tid & 63, wave = tid >> 6;         // 8 waves
    int quad = lane >> 4, l16 = lane & 15;

    // stationary weight fragments: wh/wl[ks][nt2]
    s16x8 wh[8][2], wl[8][2];
    {
        const unsigned short* bh = Wth + (size_t)(wave * 32 + l16) * EMB + quad * 8;
        const unsigned short* bl = Wtl + (size_t)(wave * 32 + l16) * EMB + quad * 8;
#pragma unroll
        for (int ks = 0; ks < 8; ++ks)
#pragma unroll
            for (int nt2 = 0; nt2 < 2; ++nt2) {
                wh[ks][nt2] = *(const s16x8*)(bh + (size_t)nt2 * 16 * EMB + ks * 32);
                wl[ks][nt2] = *(const s16x8*)(bl + (size_t)nt2 * 16 * EMB + ks * 32);
            }
    }
    float bb[2];
    if (MODE != 0) {
#pragma unroll
        for (int nt2 = 0; nt2 < 2; ++nt2) bb[nt2] = bias[wave * 32 + nt2 * 16 + l16];
    }

    int ns = (NSTRIP - blockIdx.x + (LINB - 1)) / LINB;   // 2 or 3 strips

    // staging map: u = tid + 512*i (i<4): plane=u>>10, row=(u>>5)&31, slot=u&31
    uint4 stg[4];
    {
        int nb0 = blockIdx.x * 32;
#pragma unroll
        for (int i = 0; i < 4; ++i) {
            int u = tid + 512 * i;
            int p = u >> 10, row = (u >> 5) & 31, s = u & 31;
            const unsigned short* srcp = (p ? Alo : Ahi) + (size_t)(nb0 + row) * EMB + s * 8;
            stg[i] = *(const uint4*)srcp;
        }
#pragma unroll
        for (int i = 0; i < 4; ++i) {
            int u = tid + 512 * i;
            int p = u >> 10, row = (u >> 5) & 31, s = u & 31;
            int sw = s ^ (row & 7);
            if (p) *(uint4*)&Sl[0][row][sw * 8] = stg[i];
            else   *(uint4*)&Sh[0][row][sw * 8] = stg[i];
        }
    }
    __syncthreads();

    for (int si = 0; si < ns; ++si) {
        int cur = si & 1;
        int nb = (blockIdx.x + si * LINB) * 32;

        // issue next strip's loads (hidden under MFMA phase)
        if (si + 1 < ns) {
            int nbn = (blockIdx.x + (si + 1) * LINB) * 32;
#pragma unroll
            for (int i = 0; i < 4; ++i) {
                int u = tid + 512 * i;
                int p = u >> 10, row = (u >> 5) & 31, s = u & 31;
                const unsigned short* srcp = (p ? Alo : Ahi) + (size_t)(nbn + row) * EMB + s * 8;
                stg[i] = *(const uint4*)srcp;
            }
        }

        f32x4 acc[2][2];
#pragma unroll
        for (int mt = 0; mt < 2; ++mt)
#pragma unroll
            for (int nt2 = 0; nt2 < 2; ++nt2) acc[mt][nt2] = (f32x4){0.f, 0.f, 0.f, 0.f};

#pragma unroll
        for (int ks = 0; ks < 8; ++ks) {
            s16x8 ah[2], al[2];
#pragma unroll
            for (int mt = 0; mt < 2; ++mt) {
                int row = mt * 16 + l16;
                int sw = (ks * 4 + quad) ^ (row & 7);
                ah[mt] = *(const s16x8*)&Sh[cur][row][sw * 8];
                al[mt] = *(const s16x8*)&Sl[cur][row][sw * 8];
            }
#pragma unroll
            for (int mt = 0; mt < 2; ++mt)
#pragma unroll
                for (int nt2 = 0; nt2 < 2; ++nt2) {
                    acc[mt][nt2] = __builtin_amdgcn_mfma_f32_16x16x32_bf16(ah[mt], wh[ks][nt2], acc[mt][nt2], 0, 0, 0);
                    acc[mt][nt2] = __builtin_amdgcn_mfma_f32_16x16x32_bf16(ah[mt], wl[ks][nt2], acc[mt][nt2], 0, 0, 0);
                    acc[mt][nt2] = __builtin_amdgcn_mfma_f32_16x16x32_bf16(al[mt], wh[ks][nt2], acc[mt][nt2], 0, 0, 0);
                }
        }

        // epilogue for strip si
#pragma unroll
        for (int mt = 0; mt < 2; ++mt)
#pragma unroll
            for (int r = 0; r < 4; ++r) {
                int row = nb + mt * 16 + quad * 4 + r;
#pragma unroll
                for (int nt2 = 0; nt2 < 2; ++nt2) {
                    int col = wave * 32 + nt2 * 16 + l16;
                    float v = acc[mt][nt2][r];
                    if (MODE == 0) {
                        Cf[(size_t)row * EMB + col] = v;
                    } else if (MODE == 1) {
                        v = fmaxf(v + bb[nt2], 0.f);
                        unsigned short h, l;
                        split_bf(v, h, l);
                        Chi[(size_t)row * EMB + col] = h;
                        Clo[(size_t)row * EMB + col] = l;
                    } else {
                        Cf[(size_t)row * EMB + col] = v + bb[nt2];
                    }
                }
            }

        // write next strip into the other LDS buffer; single barrier per strip
        if (si + 1 < ns) {
            int nxt = cur ^ 1;
#pragma unroll
            for (int i = 0; i < 4; ++i) {
                int u = tid + 512 * i;
                int p = u >> 10, row = (u >> 5) & 31, s = u & 31;
                int sw = s ^ (row & 7);
                if (p) *(uint4*)&Sl[nxt][row][sw * 8] = stg[i];
                else   *(uint4*)&Sh[nxt][row][sw * 8] = stg[i];
            }
            __syncthreads();
        }
    }
}

// ---------------- persistent weight-stationary K=320 conv0 GEMM ----------------
// Reads f32 x directly; hi/lo split happens ONCE per element at LDS stage-write
// (no pre-split X planes). Weights stationary in 160 VGPRs. Single-buffered
// 40KB LDS, reg prefetch of next strip. f32 out, no bias.

__global__ __launch_bounds__(512, 1) void k_lin320(
    const float* __restrict__ X,
    const unsigned short* __restrict__ Wth,
    const unsigned short* __restrict__ Wtl,
    float* __restrict__ Cf)
{
    __shared__ unsigned short Sh[32][KPAD0];
    __shared__ unsigned short Sl[32][KPAD0];
    int tid  = threadIdx.x;
    int lane = tid & 63, wave = tid >> 6;         // 8 waves
    int quad = lane >> 4, l16 = lane & 15;

    // stationary weight fragments: wh/wl[ks][nt2], ks<10
    s16x8 wh[10][2], wl[10][2];
    {
        const unsigned short* bh = Wth + (size_t)(wave * 32 + l16) * KPAD0 + quad * 8;
        const unsigned short* bl = Wtl + (size_t)(wave * 32 + l16) * KPAD0 + quad * 8;
#pragma unroll
        for (int ks = 0; ks < 10; ++ks)
#pragma unroll
            for (int nt2 = 0; nt2 < 2; ++nt2) {
                wh[ks][nt2] = *(const s16x8*)(bh + (size_t)nt2 * 16 * KPAD0 + ks * 32);
                wl[ks][nt2] = *(const s16x8*)(bl + (size_t)nt2 * 16 * KPAD0 + ks * 32);
            }
    }

    int ns = (NSTRIP - blockIdx.x + (LINB - 1)) / LINB;

    // staging map: strip = 32 rows x 80 float4 slots (k = slot*4..slot*4+3);
    // 512 thr x 5 = 2560 float4. k>=300 reads spill into the next row's data —
    // harmless (weights zero-padded there) — except the very last row (OOB): zero.
    float4 stg[5];
    auto stage_load = [&](int nb) {
#pragma unroll
        for (int i = 0; i < 5; ++i) {
            int u = tid + 512 * i;
            int row = u / 80, s = u - row * 80;
            int gr = nb + row;
            if (gr == N_NODES - 1 && s >= 75) {
                stg[i] = make_float4(0.f, 0.f, 0.f, 0.f);
            } else {
                stg[i] = *(const float4*)(X + (size_t)gr * D_IN + s * 4);
            }
        }
    };
    auto stage_write = [&]() {
#pragma unroll
        for (int i = 0; i < 5; ++i) {
            int u = tid + 512 * i;
            int row = u / 80, s = u - row * 80;
            // 16B swizzle unit = 2 float4 slots; half = s&1
            int sw = ((s >> 1) ^ (row & 7)) * 8 + (s & 1) * 4;
            float fv[4] = {stg[i].x, stg[i].y, stg[i].z, stg[i].w};
            unsigned short h[4], l[4];
#pragma unroll
            for (int j = 0; j < 4; ++j) split_bf(fv[j], h[j], l[j]);
            ushort4 hv; hv.x = h[0]; hv.y = h[1]; hv.z = h[2]; hv.w = h[3];
            ushort4 lv; lv.x = l[0]; lv.y = l[1]; lv.z = l[2]; lv.w = l[3];
            *(ushort4*)&Sh[row][sw] = hv;
            *(ushort4*)&Sl[row][sw] = lv;
        }
    };

    stage_load(blockIdx.x * 32);
    stage_write();
    __syncthreads();

    for (int si = 0; si < ns; ++si) {
        int nb = (blockIdx.x + si * LINB) * 32;

        if (si + 1 < ns) stage_load((blockIdx.x + (si + 1) * LINB) * 32);

        f32x4 acc[2][2];
#pragma unroll
        for (int mt = 0; mt < 2; ++mt)
#pragma unroll
            for (int nt2 = 0; nt2 < 2; ++nt2) acc[mt][nt2] = (f32x4){0.f, 0.f, 0.f, 0.f};

#pragma unroll
        for (int ks = 0; ks < 10; ++ks) {
            s16x8 ah[2], al[2];
#pragma unroll
            for (int mt = 0; mt < 2; ++mt) {
                int row = mt * 16 + l16;
                int sw = (ks * 4 + quad) ^ (row & 7);
                ah[mt] = *(const s16x8*)&Sh[row][sw * 8];
                al[mt] = *(const s16x8*)&Sl[row][sw * 8];
            }
#pragma unroll
            for (int mt = 0; mt < 2; ++mt)
#pragma unroll
                for (int nt2 = 0; nt2 < 2; ++nt2) {
                    acc[mt][nt2] = __builtin_amdgcn_mfma_f32_16x16x32_bf16(ah[mt], wh[ks][nt2], acc[mt][nt2], 0, 0, 0);
                    acc[mt][nt2] = __builtin_amdgcn_mfma_f32_16x16x32_bf16(ah[mt], wl[ks][nt2], acc[mt][nt2], 0, 0, 0);
                    acc[mt][nt2] = __builtin_amdgcn_mfma_f32_16x16x32_bf16(al[mt], wh[ks][nt2], acc[mt][nt2], 0, 0, 0);
                }
        }

#pragma unroll
        for (int mt = 0; mt < 2; ++mt)
#pragma unroll
            for (int r = 0; r < 4; ++r) {
                int row = nb + mt * 16 + quad * 4 + r;
#pragma unroll
                for (int nt2 = 0; nt2 < 2; ++nt2) {
                    int col = wave * 32 + nt2 * 16 + l16;
                    Cf[(size_t)row * EMB + col] = acc[mt][nt2][r];
                }
            }

        if (si + 1 < ns) {
            __syncthreads();   // all MFMA reads of LDS done
            stage_write();
            __syncthreads();
        }
    }
}

// ---------------- launch ----------------

extern "C" void kernel_launch(void* const* d_in, const int* in_sizes, int n_in,
                              void* d_out, int out_size, void* d_ws, size_t ws_size,
                              hipStream_t stream) {
    const float* x  = (const float*)d_in[0];
    const int*   ei = (const int*)d_in[1];
    const int* src = ei;
    const int* dst = ei + N_EDGES;

    const float* w[6] = {
        (const float*)d_in[2], (const float*)d_in[4], (const float*)d_in[6],
        (const float*)d_in[8], (const float*)d_in[10], (const float*)d_in[12] };
    const float* b[6] = {
        (const float*)d_in[3], (const float*)d_in[5], (const float*)d_in[7],
        (const float*)d_in[9], (const float*)d_in[11], (const float*)d_in[13] };

    char* wsp = (char*)d_ws;
    auto alloc = [&](size_t bytes) {
        char* p = wsp; wsp += (bytes + 255) & ~(size_t)255; return p;
    };
    int*   deg      = (int*)alloc(N_NODES * 4);
    int*   cursor   = (int*)alloc(N_NODES * 4);
    int*   ro       = (int*)alloc((N_NODES + 1) * 4);
    int*   part     = (int*)alloc(SCAN_NBLK * 4);
    int2*  csr      = (int2*)alloc((size_t)N_EDGES * 8);
    float* dinv     = (float*)alloc(N_NODES * 4);
    unsigned short* wth[6];
    unsigned short* wtl[6];
    wth[0] = (unsigned short*)alloc(EMB * KPAD0 * 2);
    wtl[0] = (unsigned short*)alloc(EMB * KPAD0 * 2);
    for (int i = 1; i < 6; ++i) {
        wth[i] = (unsigned short*)alloc(EMB * EMB * 2);
        wtl[i] = (unsigned short*)alloc(EMB * EMB * 2);
    }
    float* FA = (float*)alloc((size_t)N_NODES * EMB * 4);                     // f32 features
    unsigned short* Ghi = (unsigned short*)alloc((size_t)N_NODES * EMB * 2);  // plane pair A
    unsigned short* Glo = (unsigned short*)alloc((size_t)N_NODES * EMB * 2);
    unsigned short* Hhi = (unsigned short*)alloc((size_t)N_NODES * EMB * 2);  // plane pair B
    unsigned short* Hlo = (unsigned short*)alloc((size_t)N_NODES * EMB * 2);
    float* FB = (float*)d_out;                                                // d_out as scratch

    const int NB_E = (N_EDGES + 255) / 256;               // 1250
    const int ABX  = NSTRIP * 8;                          // 5000 (strip x dim-group)

    // per-node CSR build; deg+cursor zeroed by one memset (adjacent allocations)
    hipMemsetAsync(deg, 0, 2 * ((N_NODES * 4 + 255) & ~(size_t)255), stream);
    k_deg<<<NB_E, 256, 0, stream>>>(dst, deg, N_EDGES);
    k_scan_part<<<SCAN_NBLK, SCAN_TPB, 0, stream>>>(deg, part);
    k_scan_root<<<1, SCAN_TPB, 0, stream>>>(part);
    k_scan_write<<<SCAN_NBLK, SCAN_TPB, 0, stream>>>(deg, part, ro, dinv);
    k_scatter<<<NB_E, 256, 0, stream>>>(src, dst, ro, cursor, dinv, csr, N_EDGES);

    // weights: transpose + hi/lo split
    WSplitArgs wa;
    for (int i = 0; i < 6; ++i) { wa.w[i] = w[i]; wa.th[i] = wth[i]; wa.tl[i] = wtl[i]; }
    k_wsplit_all<<<WSPLITB, 256, 0, stream>>>(wa);

    // conv0 gemm: x @ W0 -> FA (f32), weight-stationary persistent, f32 staging
    k_lin320<<<LINB, 512, 0, stream>>>(x, wth[0], wtl[0], FA);

    // conv1: agg(FA)+b0,relu -> G planes ; G @ W1 -> FB (f32)
    k_agg<<<ABX, 256, 0, stream>>>(FA, ro, csr, dinv, b[0], Ghi, Glo, 1);
    k_lin<0><<<LINB, 512, 0, stream>>>(Ghi, Glo, wth[1], wtl[1], nullptr, FB, nullptr, nullptr);

    // conv2: agg(FB)+b1,relu -> G planes ; G @ W2 -> FA (f32)
    k_agg<<<ABX, 256, 0, stream>>>(FB, ro, csr, dinv, b[1], Ghi, Glo, 1);
    k_lin<0><<<LINB, 512, 0, stream>>>(Ghi, Glo, wth[2], wtl[2], nullptr, FA, nullptr, nullptr);

    // tail: agg(FA)+b2 -> G planes ; mlp1 -> H planes ; mlp2 -> G planes ; mlp3 -> out
    k_agg<<<ABX, 256, 0, stream>>>(FA, ro, csr, dinv, b[2], Ghi, Glo, 0);
    k_lin<1><<<LINB, 512, 0, stream>>>(Ghi, Glo, wth[3], wtl[3], b[3], nullptr, Hhi, Hlo);
    k_lin<1><<<LINB, 512, 0, stream>>>(Hhi, Hlo, wth[4], wtl[4], b[4], nullptr, Ghi, Glo);
    k_lin<2><<<LINB, 512, 0, stream>>>(Ghi, Glo, wth[5], wtl[5], b[5], FB, nullptr, nullptr);
}